// Round 4
// baseline (852.842 us; speedup 1.0000x reference)
//
#include <hip/hip_runtime.h>
#include <hip/hip_bf16.h>
#include <math.h>

// Problem constants (fixed by reference)
#define D_MODEL   768
#define D_STATE   16
#define D_CONV    4
#define D_INNER   1536
#define DT_RANK   48
#define BATCH     4
#define SEQ_LEN   2048
#define BL        (BATCH * SEQ_LEN)        // 8192 rows
#define NCHUNK    32
#define CHUNK     (SEQ_LEN / NCHUNK)       // 64

typedef __bf16 bf16x8 __attribute__((ext_vector_type(8)));
typedef float  f32x4  __attribute__((ext_vector_type(4)));

__device__ __forceinline__ void async_copy16(const void* g, void* l) {
    __builtin_amdgcn_global_load_lds(
        (const __attribute__((address_space(1))) void*)g,
        (__attribute__((address_space(3))) void*)l,
        16, 0, 0);
}

// ---------------------------------------------------------------------------
// Split-bf16 MFMA GEMM (NT): C[m,n] = sum_k A[m,k]*B[n,k] in ~fp32 precision.
// A: M x 2K bf16 [A_hi | A_lo], B: N x 2K bf16 [B_hi | B_lo].
// Logical K' = 3K walked as slices A:{hi,hi,lo} x B:{hi,lo,hi}
//   => C = Ah*Bh + Ah*Bl + Al*Bh   (drops Al*Bl ~ 2^-18)
// 128x128 tile, BK=32, 4 waves of 64x64 (4x4 of 16x16x32 MFMA).
//
// LDS is stored in MFMA-FRAGMENT ORDER: fragment f (16 rows x 32 k = 1024B)
// occupies [f*1024, (f+1)*1024); lane l's 16B slice is A[f*16+(l&15)][(l>>4)*8..+8].
// Staging: one global_load_lds per fragment (lane l -> base + l*16, the
// HW-required contiguous mapping). Fragment reads are ds_read_b128 at
// frag*1024 + lane*16 -> stride-16B, 2 lanes/bank per phase = conflict-free.
// (Round-3 row-major layout had 8-way conflicts: 2.9x LDS cost, MfmaUtil 26%.)
// ---------------------------------------------------------------------------
__global__ __launch_bounds__(256)
void gemm_split_nt(const __bf16* __restrict__ A, const __bf16* __restrict__ B,
                   float* __restrict__ C, int M, int N, int K, int ldc)
{
    __shared__ __bf16 Asl[128 * 32];
    __shared__ __bf16 Bsl[128 * 32];

    const int tid  = threadIdx.x;
    const int lane = tid & 63;
    const int w    = tid >> 6;
    const int wm   = (w >> 1) * 64;
    const int wn   = (w & 1) * 64;

    const int bm = blockIdx.y * 128;
    const int bn = blockIdx.x * 128;

    const long lda = 2L * K;
    const long ldb = 2L * K;

    f32x4 acc[4][4];
    #pragma unroll
    for (int i = 0; i < 4; ++i)
        #pragma unroll
        for (int j = 0; j < 4; ++j)
            acc[i][j] = (f32x4){0.f, 0.f, 0.f, 0.f};

    // staging: wave w stages fragments 2w, 2w+1 of A and of B
    const int fr = lane & 15;           // row within fragment
    const int kc = (lane >> 4) * 8;     // k offset within 32-k tile
    const int f0 = 2 * w, f1 = 2 * w + 1;
    const __bf16* Abase0 = A + (long)(bm + f0 * 16 + fr) * lda + kc;
    const __bf16* Abase1 = A + (long)(bm + f1 * 16 + fr) * lda + kc;
    const __bf16* Bbase0 = B + (long)(bn + f0 * 16 + fr) * ldb + kc;
    const __bf16* Bbase1 = B + (long)(bn + f1 * 16 + fr) * ldb + kc;
    char* AslW0 = (char*)Asl + f0 * 1024;
    char* AslW1 = (char*)Asl + f1 * 1024;
    char* BslW0 = (char*)Bsl + f0 * 1024;
    char* BslW1 = (char*)Bsl + f1 * 1024;

    // fragment-read bases (bf16 units): frag*512 + lane*8
    const int faBase = (wm >> 4);
    const int fbBase = (wn >> 4);
    const int rdOff  = lane * 8;

    const int K2 = 2 * K;
    const int KT = (3 * K) / 32;
    for (int kt = 0; kt < KT; ++kt) {
        const int kp = kt * 32;
        const int ka = (kp < K)  ? kp : kp - K;      // A slices: hi,hi,lo
        const int kb = (kp < K2) ? kp : kp - K2;     // B slices: hi,lo,hi

        __syncthreads();
        async_copy16(Abase0 + ka, AslW0);
        async_copy16(Abase1 + ka, AslW1);
        async_copy16(Bbase0 + kb, BslW0);
        async_copy16(Bbase1 + kb, BslW1);
        __syncthreads();

        bf16x8 af[4], bfr[4];
        #pragma unroll
        for (int t = 0; t < 4; ++t) {
            af[t]  = *(const bf16x8*)&Asl[(faBase + t) * 512 + rdOff];
            bfr[t] = *(const bf16x8*)&Bsl[(fbBase + t) * 512 + rdOff];
        }
        #pragma unroll
        for (int i = 0; i < 4; ++i)
            #pragma unroll
            for (int j = 0; j < 4; ++j)
                acc[i][j] = __builtin_amdgcn_mfma_f32_16x16x32_bf16(af[i], bfr[j], acc[i][j], 0, 0, 0);
    }

    // C/D layout (m89-verified): col = lane&15, row = (lane>>4)*4 + reg
    const int cn  = lane & 15;
    const int cr4 = (lane >> 4) * 4;
    #pragma unroll
    for (int i = 0; i < 4; ++i)
        #pragma unroll
        for (int j = 0; j < 4; ++j)
            #pragma unroll
            for (int r = 0; r < 4; ++r) {
                const int row = bm + wm + i * 16 + cr4 + r;
                const int col = bn + wn + j * 16 + cn;
                C[(long)row * ldc + col] = acc[i][j][r];
            }
}

// ---------------------------------------------------------------------------
// x_dbl split-K MFMA GEMM: A = xcS (8192 x 3072 bf16 split), B = W_xS
// (128-row padded panel, 80 valid), K=1536, K'=4608 -> 144 k-tiles split 4.
// grid(4, 64); partials to Pout[s][8192][128]. Same fragment-order LDS.
// ---------------------------------------------------------------------------
__global__ __launch_bounds__(256)
void gemm_xdbl(const __bf16* __restrict__ A, const __bf16* __restrict__ B,
               float* __restrict__ Pout)
{
    __shared__ __bf16 Asl[128 * 32];
    __shared__ __bf16 Bsl[128 * 32];

    const int tid  = threadIdx.x;
    const int lane = tid & 63;
    const int w    = tid >> 6;
    const int wm   = (w >> 1) * 64;
    const int wn   = (w & 1) * 64;

    const int s  = blockIdx.x;           // split-K index 0..3
    const int bm = blockIdx.y * 128;
    const long lda = 3072, ldb = 3072;
    const int K = 1536, K2 = 3072;

    f32x4 acc[4][4];
    #pragma unroll
    for (int i = 0; i < 4; ++i)
        #pragma unroll
        for (int j = 0; j < 4; ++j)
            acc[i][j] = (f32x4){0.f, 0.f, 0.f, 0.f};

    const int fr = lane & 15;
    const int kc = (lane >> 4) * 8;
    const int f0 = 2 * w, f1 = 2 * w + 1;
    const __bf16* Abase0 = A + (long)(bm + f0 * 16 + fr) * lda + kc;
    const __bf16* Abase1 = A + (long)(bm + f1 * 16 + fr) * lda + kc;
    const __bf16* Bbase0 = B + (long)(f0 * 16 + fr) * ldb + kc;
    const __bf16* Bbase1 = B + (long)(f1 * 16 + fr) * ldb + kc;
    char* AslW0 = (char*)Asl + f0 * 1024;
    char* AslW1 = (char*)Asl + f1 * 1024;
    char* BslW0 = (char*)Bsl + f0 * 1024;
    char* BslW1 = (char*)Bsl + f1 * 1024;

    const int faBase = (wm >> 4);
    const int fbBase = (wn >> 4);
    const int rdOff  = lane * 8;

    for (int kt = s * 36; kt < (s + 1) * 36; ++kt) {
        const int kp = kt * 32;
        const int ka = (kp < K)  ? kp : kp - K;
        const int kb = (kp < K2) ? kp : kp - K2;

        __syncthreads();
        async_copy16(Abase0 + ka, AslW0);
        async_copy16(Abase1 + ka, AslW1);
        async_copy16(Bbase0 + kb, BslW0);
        async_copy16(Bbase1 + kb, BslW1);
        __syncthreads();

        bf16x8 af[4], bfr[4];
        #pragma unroll
        for (int t = 0; t < 4; ++t) {
            af[t]  = *(const bf16x8*)&Asl[(faBase + t) * 512 + rdOff];
            bfr[t] = *(const bf16x8*)&Bsl[(fbBase + t) * 512 + rdOff];
        }
        #pragma unroll
        for (int i = 0; i < 4; ++i)
            #pragma unroll
            for (int j = 0; j < 4; ++j)
                acc[i][j] = __builtin_amdgcn_mfma_f32_16x16x32_bf16(af[i], bfr[j], acc[i][j], 0, 0, 0);
    }

    float* Cp = Pout + (long)s * (8192L * 128);
    const int cn  = lane & 15;
    const int cr4 = (lane >> 4) * 4;
    #pragma unroll
    for (int i = 0; i < 4; ++i)
        #pragma unroll
        for (int j = 0; j < 4; ++j)
            #pragma unroll
            for (int r = 0; r < 4; ++r) {
                const int row = bm + wm + i * 16 + cr4 + r;
                const int col = wn + j * 16 + cn;
                Cp[(long)row * 128 + col] = acc[i][j][r];
            }
}

// Reduce 4 split-K partials (ld 128) into xdbl (ld 80).
__global__ __launch_bounds__(256)
void xdbl_reduce(const float* __restrict__ Pout, float* __restrict__ xdbl)
{
    const long i = (long)blockIdx.x * 256 + threadIdx.x;   // over 8192*80
    if (i >= 8192L * 80) return;
    const long r = i / 80;
    const int  c = (int)(i - r * 80);
    const long o = r * 128 + c;
    const long st = 8192L * 128;
    xdbl[i] = (Pout[o] + Pout[o + st]) + (Pout[o + 2 * st] + Pout[o + 3 * st]);
}

// ---------------------------------------------------------------------------
// fp32 -> split-bf16 [hi|lo] rows.  src: rows x K fp32, dst: rows x 2K bf16.
// ---------------------------------------------------------------------------
__global__ __launch_bounds__(256)
void split_bf16_kernel(const float* __restrict__ src, __bf16* __restrict__ dst,
                       int K, long n)
{
    const long i = (long)blockIdx.x * 256 + threadIdx.x;
    if (i >= n) return;
    const long row = i / K;
    const int  col = (int)(i - row * K);
    const float a = src[i];
    const __bf16 h = (__bf16)a;
    const __bf16 l = (__bf16)(a - (float)h);
    __bf16* d = dst + row * (2L * K) + col;
    d[0] = h;
    d[K] = l;
}

// ---------------------------------------------------------------------------
// Tiled fp32 SGEMM (NT) — kept for the dt GEMM (K=48).
// MODE 1: softplus(v + bias[n]).
// ---------------------------------------------------------------------------
template <int MODE>
__global__ __launch_bounds__(256)
void sgemm_nt(const float* __restrict__ A, const float* __restrict__ B,
              float* __restrict__ C, const float* __restrict__ bias,
              int M, int N, int K, int lda, int ldb, int ldc)
{
    const int BM = 128, BN = 128, BK = 8;
    __shared__ float As[BK][BM];
    __shared__ float Bs[BK][BN];

    const int tid  = threadIdx.x;
    const int bm   = blockIdx.y * BM;
    const int bn   = blockIdx.x * BN;
    const int lrow = tid >> 1;
    const int lk   = (tid & 1) * 4;

    const float* Aload = A + (long)(bm + lrow) * lda + lk;
    const float* Bload = B + (long)(bn + lrow) * ldb + lk;
    const bool bvalid = (bn + lrow) < N;

    const int tx = tid & 15;
    const int ty = tid >> 4;

    float acc[8][8];
    #pragma unroll
    for (int i = 0; i < 8; ++i)
        #pragma unroll
        for (int j = 0; j < 8; ++j) acc[i][j] = 0.f;

    for (int k0 = 0; k0 < K; k0 += BK) {
        float4 av = *(const float4*)(Aload + k0);
        float4 bv = bvalid ? *(const float4*)(Bload + k0)
                           : make_float4(0.f, 0.f, 0.f, 0.f);
        __syncthreads();
        As[lk + 0][lrow] = av.x; As[lk + 1][lrow] = av.y;
        As[lk + 2][lrow] = av.z; As[lk + 3][lrow] = av.w;
        Bs[lk + 0][lrow] = bv.x; Bs[lk + 1][lrow] = bv.y;
        Bs[lk + 2][lrow] = bv.z; Bs[lk + 3][lrow] = bv.w;
        __syncthreads();

        #pragma unroll
        for (int k = 0; k < BK; ++k) {
            float4 a0 = *(const float4*)&As[k][ty * 8];
            float4 a1 = *(const float4*)&As[k][ty * 8 + 4];
            float4 b0 = *(const float4*)&Bs[k][tx * 8];
            float4 b1 = *(const float4*)&Bs[k][tx * 8 + 4];
            float a[8] = {a0.x, a0.y, a0.z, a0.w, a1.x, a1.y, a1.z, a1.w};
            float b[8] = {b0.x, b0.y, b0.z, b0.w, b1.x, b1.y, b1.z, b1.w};
            #pragma unroll
            for (int i = 0; i < 8; ++i)
                #pragma unroll
                for (int j = 0; j < 8; ++j)
                    acc[i][j] = fmaf(a[i], b[j], acc[i][j]);
        }
    }

    #pragma unroll
    for (int i = 0; i < 8; ++i) {
        const int row = bm + ty * 8 + i;
        #pragma unroll
        for (int j = 0; j < 8; ++j) {
            const int col = bn + tx * 8 + j;
            if (col < N) {
                float v = acc[i][j];
                if (MODE == 1) {
                    v += bias[col];
                    v = fmaxf(v, 0.f) + log1pf(__expf(-fabsf(v)));  // stable softplus
                }
                C[(long)row * ldc + col] = v;
            }
        }
    }
}

// ---------------------------------------------------------------------------
// Depthwise causal conv (width 4) + bias + SiLU -> xc fp32 AND xcS split-bf16.
// ---------------------------------------------------------------------------
__global__ __launch_bounds__(256)
void conv_silu_kernel(const float* __restrict__ xz,
                      const float* __restrict__ conv_w,
                      const float* __restrict__ conv_b,
                      float* __restrict__ xc,
                      __bf16* __restrict__ xcS)
{
    const long idx = (long)blockIdx.x * 256 + threadIdx.x;
    const int d  = (int)(idx % D_INNER);
    const long bl = idx / D_INNER;
    const int l  = (int)(bl % SEQ_LEN);

    const float w0 = conv_w[d * 4 + 0];
    const float w1 = conv_w[d * 4 + 1];
    const float w2 = conv_w[d * 4 + 2];
    const float w3 = conv_w[d * 4 + 3];

    const float* base = xz + bl * 3072 + d;
    float s = conv_b[d];
    if (l >= 3) s = fmaf(base[-3 * 3072], w0, s);
    if (l >= 2) s = fmaf(base[-2 * 3072], w1, s);
    if (l >= 1) s = fmaf(base[-1 * 3072], w2, s);
    s = fmaf(base[0], w3, s);
    const float sig = 1.f / (1.f + __expf(-s));
    const float v = s * sig;
    xc[bl * D_INNER + d] = v;
    const __bf16 hi = (__bf16)v;
    const __bf16 lo = (__bf16)(v - (float)hi);
    xcS[bl * 3072 + d]        = hi;
    xcS[bl * 3072 + 1536 + d] = lo;
}

// ---------------------------------------------------------------------------
// Scan phase A: per (b, d, chunk): P = prod(a_l), S = local scan (h0=0).
// ---------------------------------------------------------------------------
__global__ __launch_bounds__(256)
void scan_phaseA(const float* __restrict__ xc, const float* __restrict__ xz,
                 const float* __restrict__ xdbl, const float* __restrict__ A_log,
                 float* __restrict__ P, float* __restrict__ S)
{
    const int d = blockIdx.x * 256 + threadIdx.x;
    const int c = blockIdx.y;
    const int b = blockIdx.z;

    float An[16], Pr[16], Sr[16];
    #pragma unroll
    for (int n = 0; n < 16; ++n) {
        An[n] = -__expf(A_log[d * 16 + n]);
        Pr[n] = 1.f;
        Sr[n] = 0.f;
    }

    const long bl0 = (long)b * SEQ_LEN + (long)c * CHUNK;
    for (int l = 0; l < CHUNK; ++l) {
        const long bl = bl0 + l;
        const float dt  = xz[bl * 3072 + d];
        const float x   = xc[bl * D_INNER + d];
        const float dtx = dt * x;
        const float* bc = xdbl + bl * 80 + DT_RANK;
        #pragma unroll
        for (int n = 0; n < 16; ++n) {
            const float a = __expf(dt * An[n]);
            Pr[n] *= a;
            Sr[n] = fmaf(a, Sr[n], dtx * bc[n]);
        }
    }

    const long base = ((long)(b * NCHUNK + c) * 16) * D_INNER + d;
    #pragma unroll
    for (int n = 0; n < 16; ++n) {
        P[base + (long)n * D_INNER] = Pr[n];
        S[base + (long)n * D_INNER] = Sr[n];
    }
}

// ---------------------------------------------------------------------------
// Scan phase B: sequential chunk-combine per (b, d): H[c] = h_in for chunk c.
// ---------------------------------------------------------------------------
__global__ __launch_bounds__(256)
void scan_phaseB(const float* __restrict__ P, const float* __restrict__ S,
                 float* __restrict__ H)
{
    const int t = blockIdx.x * 256 + threadIdx.x;
    const int d = t % D_INNER;
    const int b = t / D_INNER;

    float h[16];
    #pragma unroll
    for (int n = 0; n < 16; ++n) h[n] = 0.f;

    for (int c = 0; c < NCHUNK; ++c) {
        const long base = ((long)(b * NCHUNK + c) * 16) * D_INNER + d;
        #pragma unroll
        for (int n = 0; n < 16; ++n) {
            const long i = base + (long)n * D_INNER;
            H[i] = h[n];
            h[n] = fmaf(P[i], h[n], S[i]);
        }
    }
}

// ---------------------------------------------------------------------------
// Scan phase C: re-run chunks from correct h_in, emit y, gate with silu(z),
// write y as split-bf16 [hi|lo] rows (row stride 3072) for the MFMA out-GEMM.
// ---------------------------------------------------------------------------
__global__ __launch_bounds__(256)
void scan_phaseC(const float* __restrict__ xc, const float* __restrict__ xz,
                 const float* __restrict__ xdbl, const float* __restrict__ A_log,
                 const float* __restrict__ Dp, const float* __restrict__ H,
                 __bf16* __restrict__ yS)
{
    const int d = blockIdx.x * 256 + threadIdx.x;
    const int c = blockIdx.y;
    const int b = blockIdx.z;

    float An[16], h[16];
    const long hbase = ((long)(b * NCHUNK + c) * 16) * D_INNER + d;
    #pragma unroll
    for (int n = 0; n < 16; ++n) {
        An[n] = -__expf(A_log[d * 16 + n]);
        h[n]  = H[hbase + (long)n * D_INNER];
    }
    const float Dd = Dp[d];

    const long bl0 = (long)b * SEQ_LEN + (long)c * CHUNK;
    for (int l = 0; l < CHUNK; ++l) {
        const long bl = bl0 + l;
        const float dt  = xz[bl * 3072 + d];
        const float x   = xc[bl * D_INNER + d];
        const float dtx = dt * x;
        const float* bc = xdbl + bl * 80 + DT_RANK;
        float y = Dd * x;
        #pragma unroll
        for (int n = 0; n < 16; ++n) {
            const float a = __expf(dt * An[n]);
            h[n] = fmaf(a, h[n], dtx * bc[n]);
            y = fmaf(h[n], bc[16 + n], y);
        }
        const float z  = xz[bl * 3072 + D_INNER + d];
        const float sz = z / (1.f + __expf(-z));
        const float v  = y * sz;
        const __bf16 hi = (__bf16)v;
        const __bf16 lo = (__bf16)(v - (float)hi);
        yS[bl * 3072 + d]        = hi;
        yS[bl * 3072 + 1536 + d] = lo;
    }
}

// ---------------------------------------------------------------------------
extern "C" void kernel_launch(void* const* d_in, const int* in_sizes, int n_in,
                              void* d_out, int out_size, void* d_ws, size_t ws_size,
                              hipStream_t stream)
{
    const float* x      = (const float*)d_in[0];   // (4,2048,768)
    const float* W_in   = (const float*)d_in[1];   // (3072,768)
    const float* conv_w = (const float*)d_in[2];   // (1536,1,4)
    const float* conv_b = (const float*)d_in[3];   // (1536,)
    const float* W_x    = (const float*)d_in[4];   // (80,1536)
    const float* W_dt   = (const float*)d_in[5];   // (1536,48)
    const float* b_dt   = (const float*)d_in[6];   // (1536,)
    const float* A_log  = (const float*)d_in[7];   // (1536,16)
    const float* D_p    = (const float*)d_in[8];   // (1536,)
    const float* W_out  = (const float*)d_in[9];   // (768,1536)
    float* out = (float*)d_out;                    // (4,2048,768)

    // ---- workspace carve (with region overlays), ~239 MB ----------------
    char* p = (char*)d_ws;
    auto take = [&](size_t bytes) { char* r = p; p += (bytes + 255) & ~(size_t)255; return r; };

    float*  xz    = (float*)take((size_t)BL * 3072 * 4);    // 100.7 MB (dt | z)
    float*  xc    = (float*)take((size_t)BL * 1536 * 4);    //  50.3 MB
    float*  xdbl  = (float*)take((size_t)BL * 80 * 4);      //   2.6 MB
    float*  H     = (float*)take((size_t)BATCH * NCHUNK * 16 * D_INNER * 4); // 12.6 MB
    __bf16* wOutS = (__bf16*)take(768L * 3072 * 2);         //   4.7 MB
    __bf16* wXS   = (__bf16*)take(128L * 3072 * 2);         //   0.8 MB (80 valid rows)
    float*  Pout  = (float*)take(4L * 8192 * 128 * 4);      //  16.8 MB split-K partials

    // REGION (50.4 MB), time-multiplexed:
    //   phase 1:   xS (25.2MB) + wInS (9.4MB)
    //   phase 2-3: xcS (8192x3072 bf16 = 50.3MB)
    //   phase 6-7: P (12.6MB) + S (12.6MB)
    //   phase 8-9: yS (50.3MB)
    char* region = take(50331648);
    __bf16* xS   = (__bf16*)region;
    __bf16* wInS = (__bf16*)(region + 25165824);
    __bf16* xcS  = (__bf16*)region;
    float*  P    = (float*)region;
    float*  S    = (float*)(region + 12582912);
    __bf16* yS   = (__bf16*)region;

    // 0) split conversions
    {
        const long nx = (long)BL * 768;
        split_bf16_kernel<<<(int)((nx + 255) / 256), 256, 0, stream>>>(x, xS, 768, nx);
        const long nw = 3072L * 768;
        split_bf16_kernel<<<(int)((nw + 255) / 256), 256, 0, stream>>>(W_in, wInS, 768, nw);
        const long no = 768L * 1536;
        split_bf16_kernel<<<(int)((no + 255) / 256), 256, 0, stream>>>(W_out, wOutS, 1536, no);
        const long nxw = 80L * 1536;
        split_bf16_kernel<<<(int)((nxw + 255) / 256), 256, 0, stream>>>(W_x, wXS, 1536, nxw);
    }
    // 1) xz = x @ W_in^T via split-bf16 MFMA (M=8192, N=3072, K=768)
    {
        dim3 grid(3072 / 128, BL / 128);
        gemm_split_nt<<<grid, 256, 0, stream>>>(xS, wInS, xz, BL, 3072, 768, 3072);
    }
    // 2) depthwise conv + bias + SiLU -> xc (fp32) + xcS (split-bf16; overlays xS)
    {
        const long total = (long)BL * D_INNER;
        conv_silu_kernel<<<(int)(total / 256), 256, 0, stream>>>(xz, conv_w, conv_b, xc, xcS);
    }
    // 3) x_dbl split-K MFMA: Pout[s] = xcS @ wXS^T chunks  (grid 4x64)
    {
        dim3 grid(4, BL / 128);
        gemm_xdbl<<<grid, 256, 0, stream>>>(xcS, wXS, Pout);
    }
    // 4) reduce partials -> xdbl (ld 80)
    {
        const long n = 8192L * 80;
        xdbl_reduce<<<(int)((n + 255) / 256), 256, 0, stream>>>(Pout, xdbl);
    }
    // 5) dt = softplus(x_dbl[:, :48] @ W_dt^T + b_dt) -> xz cols 0..1535 (fp32)
    {
        dim3 grid(1536 / 128, BL / 128);
        sgemm_nt<1><<<grid, 256, 0, stream>>>(xdbl, W_dt, xz, b_dt,
                                              BL, 1536, 48, 80, 48, 3072);
    }
    // 6) scan phase A  (P,S overlay region; xcS dead after phase 3)
    {
        dim3 grid(D_INNER / 256, NCHUNK, BATCH);
        scan_phaseA<<<grid, 256, 0, stream>>>(xc, xz, xdbl, A_log, P, S);
    }
    // 7) scan phase B
    scan_phaseB<<<(BATCH * D_INNER) / 256, 256, 0, stream>>>(P, S, H);
    // 8) scan phase C -> yS (split-bf16; P,S dead)
    {
        dim3 grid(D_INNER / 256, NCHUNK, BATCH);
        scan_phaseC<<<grid, 256, 0, stream>>>(xc, xz, xdbl, A_log, D_p, H, yS);
    }
    // 9) out = y @ W_out^T via split-bf16 MFMA (M=8192, N=768, K=1536)
    {
        dim3 grid(768 / 128, BL / 128);
        gemm_split_nt<<<grid, 256, 0, stream>>>(yS, wOutS, out, BL, 768, 1536, 768);
    }
}

// Round 5
// 744.356 us; speedup vs baseline: 1.1457x; 1.1457x over previous
//
#include <hip/hip_runtime.h>
#include <hip/hip_bf16.h>
#include <math.h>

// Problem constants (fixed by reference)
#define D_MODEL   768
#define D_STATE   16
#define D_CONV    4
#define D_INNER   1536
#define DT_RANK   48
#define BATCH     4
#define SEQ_LEN   2048
#define BL        (BATCH * SEQ_LEN)        // 8192 rows
#define NCHUNK    32
#define CHUNK     (SEQ_LEN / NCHUNK)       // 64

typedef __bf16 bf16x8 __attribute__((ext_vector_type(8)));
typedef float  f32x4  __attribute__((ext_vector_type(4)));

__device__ __forceinline__ void async_copy16(const void* g, void* l) {
    __builtin_amdgcn_global_load_lds(
        (const __attribute__((address_space(1))) void*)g,
        (__attribute__((address_space(3))) void*)l,
        16, 0, 0);
}

// ---------------------------------------------------------------------------
// Split-bf16 MFMA GEMM (NT): C[m,n] = sum_k A[m,k]*B[n,k] in ~fp32 precision.
// A: M x 2K bf16 [A_hi | A_lo], B: N x 2K bf16 [B_hi | B_lo].
// Logical K' = 3K walked as slices A:{hi,hi,lo} x B:{hi,lo,hi}
//   => C = Ah*Bh + Ah*Bl + Al*Bh   (drops Al*Bl ~ 2^-18)
// 128x128 tile, BK=32, 4 waves of 64x64 (4x4 of 16x16x32 MFMA).
//
// LDS: row-major 64B rows with XOR-SWIZZLED k-chunks.  Slot (r, c) holds
// global chunk c ^ ((r>>2)&3).  Staging keeps round-3 coalescing (lanes 0-3
// cover one contiguous 64B row segment, merely permuted within it — the
// swizzle is applied on the GLOBAL side since global_load_lds pins the LDS
// dest to base+lane*16).  Fragment ds_read_b128 at
// r*64 + ((lane>>4)^((lane>>2)&3))*16 -> 2 lanes/bank-group = free (m136).
// Round 3 (no swizzle): 8-way conflicts, MfmaUtil 26%.  Round 4 (fragment-
// order LDS): conflict-free but uncoalesced VMEM, regressed. This keeps both.
// ---------------------------------------------------------------------------
__global__ __launch_bounds__(256)
void gemm_split_nt(const __bf16* __restrict__ A, const __bf16* __restrict__ B,
                   float* __restrict__ C, int M, int N, int K, int ldc)
{
    __shared__ __bf16 Asl[128 * 32];
    __shared__ __bf16 Bsl[128 * 32];

    const int tid  = threadIdx.x;
    const int lane = tid & 63;
    const int w    = tid >> 6;
    const int wm   = (w >> 1) * 64;
    const int wn   = (w & 1) * 64;

    const int bm = blockIdx.y * 128;
    const int bn = blockIdx.x * 128;

    const long lda = 2L * K;
    const long ldb = 2L * K;

    f32x4 acc[4][4];
    #pragma unroll
    for (int i = 0; i < 4; ++i)
        #pragma unroll
        for (int j = 0; j < 4; ++j)
            acc[i][j] = (f32x4){0.f, 0.f, 0.f, 0.f};

    // staging: wave w stages rows [w*32, w*32+32); lane l -> row w*32+(l>>2),
    // global k-chunk (l&3)^((l>>4)&3)  [== (l&3)^((srow>>2)&3), both instrs]
    const int srow = w * 32 + (lane >> 2);
    const int kc8  = (((lane & 3) ^ ((lane >> 4) & 3))) * 8;   // swizzled chunk
    const __bf16* Abase = A + (long)(bm + srow) * lda + kc8;
    const __bf16* Bbase = B + (long)(bn + srow) * ldb + kc8;
    char* AslW = (char*)Asl + (w * 32) * 64;
    char* BslW = (char*)Bsl + (w * 32) * 64;

    // fragment-read k-slot (bf16 units): ((lane>>4) ^ ((lane>>2)&3)) * 8
    const int rdK = (((lane >> 4) ^ ((lane >> 2) & 3))) * 8;
    const int fr  = lane & 15;

    const int K2 = 2 * K;
    const int KT = (3 * K) / 32;
    for (int kt = 0; kt < KT; ++kt) {
        const int kp = kt * 32;
        const int ka = (kp < K)  ? kp : kp - K;      // A slices: hi,hi,lo
        const int kb = (kp < K2) ? kp : kp - K2;     // B slices: hi,lo,hi

        __syncthreads();
        async_copy16(Abase + ka,            AslW);
        async_copy16(Abase + 16 * lda + ka, AslW + 16 * 64);
        async_copy16(Bbase + kb,            BslW);
        async_copy16(Bbase + 16 * ldb + kb, BslW + 16 * 64);
        __syncthreads();

        bf16x8 af[4], bfr[4];
        #pragma unroll
        for (int t = 0; t < 4; ++t) {
            af[t]  = *(const bf16x8*)&Asl[(wm + t * 16 + fr) * 32 + rdK];
            bfr[t] = *(const bf16x8*)&Bsl[(wn + t * 16 + fr) * 32 + rdK];
        }
        #pragma unroll
        for (int i = 0; i < 4; ++i)
            #pragma unroll
            for (int j = 0; j < 4; ++j)
                acc[i][j] = __builtin_amdgcn_mfma_f32_16x16x32_bf16(af[i], bfr[j], acc[i][j], 0, 0, 0);
    }

    // C/D layout (m89-verified): col = lane&15, row = (lane>>4)*4 + reg
    const int cn  = lane & 15;
    const int cr4 = (lane >> 4) * 4;
    #pragma unroll
    for (int i = 0; i < 4; ++i)
        #pragma unroll
        for (int j = 0; j < 4; ++j)
            #pragma unroll
            for (int r = 0; r < 4; ++r) {
                const int row = bm + wm + i * 16 + cr4 + r;
                const int col = bn + wn + j * 16 + cn;
                C[(long)row * ldc + col] = acc[i][j][r];
            }
}

// ---------------------------------------------------------------------------
// x_dbl split-K MFMA GEMM: A = xcS (8192 x 3072 bf16 split), B = W_xS
// (128-row padded panel, 80 valid), K=1536, K'=4608 -> 144 k-tiles split 4.
// grid(4, 64); partials to Pout[s][8192][128]. Same swizzled LDS as above.
// ---------------------------------------------------------------------------
__global__ __launch_bounds__(256)
void gemm_xdbl(const __bf16* __restrict__ A, const __bf16* __restrict__ B,
               float* __restrict__ Pout)
{
    __shared__ __bf16 Asl[128 * 32];
    __shared__ __bf16 Bsl[128 * 32];

    const int tid  = threadIdx.x;
    const int lane = tid & 63;
    const int w    = tid >> 6;
    const int wm   = (w >> 1) * 64;
    const int wn   = (w & 1) * 64;

    const int s  = blockIdx.x;           // split-K index 0..3
    const int bm = blockIdx.y * 128;
    const long lda = 3072, ldb = 3072;
    const int K = 1536, K2 = 3072;

    f32x4 acc[4][4];
    #pragma unroll
    for (int i = 0; i < 4; ++i)
        #pragma unroll
        for (int j = 0; j < 4; ++j)
            acc[i][j] = (f32x4){0.f, 0.f, 0.f, 0.f};

    const int srow = w * 32 + (lane >> 2);
    const int kc8  = (((lane & 3) ^ ((lane >> 4) & 3))) * 8;
    const __bf16* Abase = A + (long)(bm + srow) * lda + kc8;
    const __bf16* Bbase = B + (long)srow * ldb + kc8;
    char* AslW = (char*)Asl + (w * 32) * 64;
    char* BslW = (char*)Bsl + (w * 32) * 64;

    const int rdK = (((lane >> 4) ^ ((lane >> 2) & 3))) * 8;
    const int fr  = lane & 15;

    for (int kt = s * 36; kt < (s + 1) * 36; ++kt) {
        const int kp = kt * 32;
        const int ka = (kp < K)  ? kp : kp - K;
        const int kb = (kp < K2) ? kp : kp - K2;

        __syncthreads();
        async_copy16(Abase + ka,            AslW);
        async_copy16(Abase + 16 * lda + ka, AslW + 16 * 64);
        async_copy16(Bbase + kb,            BslW);
        async_copy16(Bbase + 16 * ldb + kb, BslW + 16 * 64);
        __syncthreads();

        bf16x8 af[4], bfr[4];
        #pragma unroll
        for (int t = 0; t < 4; ++t) {
            af[t]  = *(const bf16x8*)&Asl[(wm + t * 16 + fr) * 32 + rdK];
            bfr[t] = *(const bf16x8*)&Bsl[(wn + t * 16 + fr) * 32 + rdK];
        }
        #pragma unroll
        for (int i = 0; i < 4; ++i)
            #pragma unroll
            for (int j = 0; j < 4; ++j)
                acc[i][j] = __builtin_amdgcn_mfma_f32_16x16x32_bf16(af[i], bfr[j], acc[i][j], 0, 0, 0);
    }

    float* Cp = Pout + (long)s * (8192L * 128);
    const int cn  = lane & 15;
    const int cr4 = (lane >> 4) * 4;
    #pragma unroll
    for (int i = 0; i < 4; ++i)
        #pragma unroll
        for (int j = 0; j < 4; ++j)
            #pragma unroll
            for (int r = 0; r < 4; ++r) {
                const int row = bm + wm + i * 16 + cr4 + r;
                const int col = wn + j * 16 + cn;
                Cp[(long)row * 128 + col] = acc[i][j][r];
            }
}

// Reduce 4 split-K partials (ld 128) into xdbl (ld 80).
__global__ __launch_bounds__(256)
void xdbl_reduce(const float* __restrict__ Pout, float* __restrict__ xdbl)
{
    const long i = (long)blockIdx.x * 256 + threadIdx.x;   // over 8192*80
    if (i >= 8192L * 80) return;
    const long r = i / 80;
    const int  c = (int)(i - r * 80);
    const long o = r * 128 + c;
    const long st = 8192L * 128;
    xdbl[i] = (Pout[o] + Pout[o + st]) + (Pout[o + 2 * st] + Pout[o + 3 * st]);
}

// ---------------------------------------------------------------------------
// fp32 -> split-bf16 [hi|lo] rows.  src: rows x K fp32, dst: rows x 2K bf16.
// ---------------------------------------------------------------------------
__global__ __launch_bounds__(256)
void split_bf16_kernel(const float* __restrict__ src, __bf16* __restrict__ dst,
                       int K, long n)
{
    const long i = (long)blockIdx.x * 256 + threadIdx.x;
    if (i >= n) return;
    const long row = i / K;
    const int  col = (int)(i - row * K);
    const float a = src[i];
    const __bf16 h = (__bf16)a;
    const __bf16 l = (__bf16)(a - (float)h);
    __bf16* d = dst + row * (2L * K) + col;
    d[0] = h;
    d[K] = l;
}

// ---------------------------------------------------------------------------
// Tiled fp32 SGEMM (NT) — kept for the dt GEMM (K=48).
// MODE 1: softplus(v + bias[n]).
// ---------------------------------------------------------------------------
template <int MODE>
__global__ __launch_bounds__(256)
void sgemm_nt(const float* __restrict__ A, const float* __restrict__ B,
              float* __restrict__ C, const float* __restrict__ bias,
              int M, int N, int K, int lda, int ldb, int ldc)
{
    const int BM = 128, BN = 128, BK = 8;
    __shared__ float As[BK][BM];
    __shared__ float Bs[BK][BN];

    const int tid  = threadIdx.x;
    const int bm   = blockIdx.y * BM;
    const int bn   = blockIdx.x * BN;
    const int lrow = tid >> 1;
    const int lk   = (tid & 1) * 4;

    const float* Aload = A + (long)(bm + lrow) * lda + lk;
    const float* Bload = B + (long)(bn + lrow) * ldb + lk;
    const bool bvalid = (bn + lrow) < N;

    const int tx = tid & 15;
    const int ty = tid >> 4;

    float acc[8][8];
    #pragma unroll
    for (int i = 0; i < 8; ++i)
        #pragma unroll
        for (int j = 0; j < 8; ++j) acc[i][j] = 0.f;

    for (int k0 = 0; k0 < K; k0 += BK) {
        float4 av = *(const float4*)(Aload + k0);
        float4 bv = bvalid ? *(const float4*)(Bload + k0)
                           : make_float4(0.f, 0.f, 0.f, 0.f);
        __syncthreads();
        As[lk + 0][lrow] = av.x; As[lk + 1][lrow] = av.y;
        As[lk + 2][lrow] = av.z; As[lk + 3][lrow] = av.w;
        Bs[lk + 0][lrow] = bv.x; Bs[lk + 1][lrow] = bv.y;
        Bs[lk + 2][lrow] = bv.z; Bs[lk + 3][lrow] = bv.w;
        __syncthreads();

        #pragma unroll
        for (int k = 0; k < BK; ++k) {
            float4 a0 = *(const float4*)&As[k][ty * 8];
            float4 a1 = *(const float4*)&As[k][ty * 8 + 4];
            float4 b0 = *(const float4*)&Bs[k][tx * 8];
            float4 b1 = *(const float4*)&Bs[k][tx * 8 + 4];
            float a[8] = {a0.x, a0.y, a0.z, a0.w, a1.x, a1.y, a1.z, a1.w};
            float b[8] = {b0.x, b0.y, b0.z, b0.w, b1.x, b1.y, b1.z, b1.w};
            #pragma unroll
            for (int i = 0; i < 8; ++i)
                #pragma unroll
                for (int j = 0; j < 8; ++j)
                    acc[i][j] = fmaf(a[i], b[j], acc[i][j]);
        }
    }

    #pragma unroll
    for (int i = 0; i < 8; ++i) {
        const int row = bm + ty * 8 + i;
        #pragma unroll
        for (int j = 0; j < 8; ++j) {
            const int col = bn + tx * 8 + j;
            if (col < N) {
                float v = acc[i][j];
                if (MODE == 1) {
                    v += bias[col];
                    v = fmaxf(v, 0.f) + log1pf(__expf(-fabsf(v)));  // stable softplus
                }
                C[(long)row * ldc + col] = v;
            }
        }
    }
}

// ---------------------------------------------------------------------------
// Depthwise causal conv (width 4) + bias + SiLU -> xc fp32 AND xcS split-bf16.
// ---------------------------------------------------------------------------
__global__ __launch_bounds__(256)
void conv_silu_kernel(const float* __restrict__ xz,
                      const float* __restrict__ conv_w,
                      const float* __restrict__ conv_b,
                      float* __restrict__ xc,
                      __bf16* __restrict__ xcS)
{
    const long idx = (long)blockIdx.x * 256 + threadIdx.x;
    const int d  = (int)(idx % D_INNER);
    const long bl = idx / D_INNER;
    const int l  = (int)(bl % SEQ_LEN);

    const float w0 = conv_w[d * 4 + 0];
    const float w1 = conv_w[d * 4 + 1];
    const float w2 = conv_w[d * 4 + 2];
    const float w3 = conv_w[d * 4 + 3];

    const float* base = xz + bl * 3072 + d;
    float s = conv_b[d];
    if (l >= 3) s = fmaf(base[-3 * 3072], w0, s);
    if (l >= 2) s = fmaf(base[-2 * 3072], w1, s);
    if (l >= 1) s = fmaf(base[-1 * 3072], w2, s);
    s = fmaf(base[0], w3, s);
    const float sig = 1.f / (1.f + __expf(-s));
    const float v = s * sig;
    xc[bl * D_INNER + d] = v;
    const __bf16 hi = (__bf16)v;
    const __bf16 lo = (__bf16)(v - (float)hi);
    xcS[bl * 3072 + d]        = hi;
    xcS[bl * 3072 + 1536 + d] = lo;
}

// ---------------------------------------------------------------------------
// Scan phase A: per (b, d, chunk): P = prod(a_l), S = local scan (h0=0).
// ---------------------------------------------------------------------------
__global__ __launch_bounds__(256)
void scan_phaseA(const float* __restrict__ xc, const float* __restrict__ xz,
                 const float* __restrict__ xdbl, const float* __restrict__ A_log,
                 float* __restrict__ P, float* __restrict__ S)
{
    const int d = blockIdx.x * 256 + threadIdx.x;
    const int c = blockIdx.y;
    const int b = blockIdx.z;

    float An[16], Pr[16], Sr[16];
    #pragma unroll
    for (int n = 0; n < 16; ++n) {
        An[n] = -__expf(A_log[d * 16 + n]);
        Pr[n] = 1.f;
        Sr[n] = 0.f;
    }

    const long bl0 = (long)b * SEQ_LEN + (long)c * CHUNK;
    for (int l = 0; l < CHUNK; ++l) {
        const long bl = bl0 + l;
        const float dt  = xz[bl * 3072 + d];
        const float x   = xc[bl * D_INNER + d];
        const float dtx = dt * x;
        const float* bc = xdbl + bl * 80 + DT_RANK;
        #pragma unroll
        for (int n = 0; n < 16; ++n) {
            const float a = __expf(dt * An[n]);
            Pr[n] *= a;
            Sr[n] = fmaf(a, Sr[n], dtx * bc[n]);
        }
    }

    const long base = ((long)(b * NCHUNK + c) * 16) * D_INNER + d;
    #pragma unroll
    for (int n = 0; n < 16; ++n) {
        P[base + (long)n * D_INNER] = Pr[n];
        S[base + (long)n * D_INNER] = Sr[n];
    }
}

// ---------------------------------------------------------------------------
// Scan phase B: sequential chunk-combine per (b, d): H[c] = h_in for chunk c.
// ---------------------------------------------------------------------------
__global__ __launch_bounds__(256)
void scan_phaseB(const float* __restrict__ P, const float* __restrict__ S,
                 float* __restrict__ H)
{
    const int t = blockIdx.x * 256 + threadIdx.x;
    const int d = t % D_INNER;
    const int b = t / D_INNER;

    float h[16];
    #pragma unroll
    for (int n = 0; n < 16; ++n) h[n] = 0.f;

    for (int c = 0; c < NCHUNK; ++c) {
        const long base = ((long)(b * NCHUNK + c) * 16) * D_INNER + d;
        #pragma unroll
        for (int n = 0; n < 16; ++n) {
            const long i = base + (long)n * D_INNER;
            H[i] = h[n];
            h[n] = fmaf(P[i], h[n], S[i]);
        }
    }
}

// ---------------------------------------------------------------------------
// Scan phase C: re-run chunks from correct h_in, emit y, gate with silu(z),
// write y as split-bf16 [hi|lo] rows (row stride 3072) for the MFMA out-GEMM.
// ---------------------------------------------------------------------------
__global__ __launch_bounds__(256)
void scan_phaseC(const float* __restrict__ xc, const float* __restrict__ xz,
                 const float* __restrict__ xdbl, const float* __restrict__ A_log,
                 const float* __restrict__ Dp, const float* __restrict__ H,
                 __bf16* __restrict__ yS)
{
    const int d = blockIdx.x * 256 + threadIdx.x;
    const int c = blockIdx.y;
    const int b = blockIdx.z;

    float An[16], h[16];
    const long hbase = ((long)(b * NCHUNK + c) * 16) * D_INNER + d;
    #pragma unroll
    for (int n = 0; n < 16; ++n) {
        An[n] = -__expf(A_log[d * 16 + n]);
        h[n]  = H[hbase + (long)n * D_INNER];
    }
    const float Dd = Dp[d];

    const long bl0 = (long)b * SEQ_LEN + (long)c * CHUNK;
    for (int l = 0; l < CHUNK; ++l) {
        const long bl = bl0 + l;
        const float dt  = xz[bl * 3072 + d];
        const float x   = xc[bl * D_INNER + d];
        const float dtx = dt * x;
        const float* bc = xdbl + bl * 80 + DT_RANK;
        float y = Dd * x;
        #pragma unroll
        for (int n = 0; n < 16; ++n) {
            const float a = __expf(dt * An[n]);
            h[n] = fmaf(a, h[n], dtx * bc[n]);
            y = fmaf(h[n], bc[16 + n], y);
        }
        const float z  = xz[bl * 3072 + D_INNER + d];
        const float sz = z / (1.f + __expf(-z));
        const float v  = y * sz;
        const __bf16 hi = (__bf16)v;
        const __bf16 lo = (__bf16)(v - (float)hi);
        yS[bl * 3072 + d]        = hi;
        yS[bl * 3072 + 1536 + d] = lo;
    }
}

// ---------------------------------------------------------------------------
extern "C" void kernel_launch(void* const* d_in, const int* in_sizes, int n_in,
                              void* d_out, int out_size, void* d_ws, size_t ws_size,
                              hipStream_t stream)
{
    const float* x      = (const float*)d_in[0];   // (4,2048,768)
    const float* W_in   = (const float*)d_in[1];   // (3072,768)
    const float* conv_w = (const float*)d_in[2];   // (1536,1,4)
    const float* conv_b = (const float*)d_in[3];   // (1536,)
    const float* W_x    = (const float*)d_in[4];   // (80,1536)
    const float* W_dt   = (const float*)d_in[5];   // (1536,48)
    const float* b_dt   = (const float*)d_in[6];   // (1536,)
    const float* A_log  = (const float*)d_in[7];   // (1536,16)
    const float* D_p    = (const float*)d_in[8];   // (1536,)
    const float* W_out  = (const float*)d_in[9];   // (768,1536)
    float* out = (float*)d_out;                    // (4,2048,768)

    // ---- workspace carve (with region overlays), ~239 MB ----------------
    char* p = (char*)d_ws;
    auto take = [&](size_t bytes) { char* r = p; p += (bytes + 255) & ~(size_t)255; return r; };

    float*  xz    = (float*)take((size_t)BL * 3072 * 4);    // 100.7 MB (dt | z)
    float*  xc    = (float*)take((size_t)BL * 1536 * 4);    //  50.3 MB
    float*  xdbl  = (float*)take((size_t)BL * 80 * 4);      //   2.6 MB
    float*  H     = (float*)take((size_t)BATCH * NCHUNK * 16 * D_INNER * 4); // 12.6 MB
    __bf16* wOutS = (__bf16*)take(768L * 3072 * 2);         //   4.7 MB
    __bf16* wXS   = (__bf16*)take(128L * 3072 * 2);         //   0.8 MB (80 valid rows)
    float*  Pout  = (float*)take(4L * 8192 * 128 * 4);      //  16.8 MB split-K partials

    // REGION (50.4 MB), time-multiplexed:
    //   phase 1:   xS (25.2MB) + wInS (9.4MB)
    //   phase 2-3: xcS (8192x3072 bf16 = 50.3MB)
    //   phase 6-7: P (12.6MB) + S (12.6MB)
    //   phase 8-9: yS (50.3MB)
    char* region = take(50331648);
    __bf16* xS   = (__bf16*)region;
    __bf16* wInS = (__bf16*)(region + 25165824);
    __bf16* xcS  = (__bf16*)region;
    float*  P    = (float*)region;
    float*  S    = (float*)(region + 12582912);
    __bf16* yS   = (__bf16*)region;

    // 0) split conversions
    {
        const long nx = (long)BL * 768;
        split_bf16_kernel<<<(int)((nx + 255) / 256), 256, 0, stream>>>(x, xS, 768, nx);
        const long nw = 3072L * 768;
        split_bf16_kernel<<<(int)((nw + 255) / 256), 256, 0, stream>>>(W_in, wInS, 768, nw);
        const long no = 768L * 1536;
        split_bf16_kernel<<<(int)((no + 255) / 256), 256, 0, stream>>>(W_out, wOutS, 1536, no);
        const long nxw = 80L * 1536;
        split_bf16_kernel<<<(int)((nxw + 255) / 256), 256, 0, stream>>>(W_x, wXS, 1536, nxw);
    }
    // 1) xz = x @ W_in^T via split-bf16 MFMA (M=8192, N=3072, K=768)
    {
        dim3 grid(3072 / 128, BL / 128);
        gemm_split_nt<<<grid, 256, 0, stream>>>(xS, wInS, xz, BL, 3072, 768, 3072);
    }
    // 2) depthwise conv + bias + SiLU -> xc (fp32) + xcS (split-bf16; overlays xS)
    {
        const long total = (long)BL * D_INNER;
        conv_silu_kernel<<<(int)(total / 256), 256, 0, stream>>>(xz, conv_w, conv_b, xc, xcS);
    }
    // 3) x_dbl split-K MFMA: Pout[s] = xcS @ wXS^T chunks  (grid 4x64)
    {
        dim3 grid(4, BL / 128);
        gemm_xdbl<<<grid, 256, 0, stream>>>(xcS, wXS, Pout);
    }
    // 4) reduce partials -> xdbl (ld 80)
    {
        const long n = 8192L * 80;
        xdbl_reduce<<<(int)((n + 255) / 256), 256, 0, stream>>>(Pout, xdbl);
    }
    // 5) dt = softplus(x_dbl[:, :48] @ W_dt^T + b_dt) -> xz cols 0..1535 (fp32)
    {
        dim3 grid(1536 / 128, BL / 128);
        sgemm_nt<1><<<grid, 256, 0, stream>>>(xdbl, W_dt, xz, b_dt,
                                              BL, 1536, 48, 80, 48, 3072);
    }
    // 6) scan phase A  (P,S overlay region; xcS dead after phase 3)
    {
        dim3 grid(D_INNER / 256, NCHUNK, BATCH);
        scan_phaseA<<<grid, 256, 0, stream>>>(xc, xz, xdbl, A_log, P, S);
    }
    // 7) scan phase B
    scan_phaseB<<<(BATCH * D_INNER) / 256, 256, 0, stream>>>(P, S, H);
    // 8) scan phase C -> yS (split-bf16; P,S dead)
    {
        dim3 grid(D_INNER / 256, NCHUNK, BATCH);
        scan_phaseC<<<grid, 256, 0, stream>>>(xc, xz, xdbl, A_log, D_p, H, yS);
    }
    // 9) out = y @ W_out^T via split-bf16 MFMA (M=8192, N=768, K=1536)
    {
        dim3 grid(768 / 128, BL / 128);
        gemm_split_nt<<<grid, 256, 0, stream>>>(yS, wOutS, out, BL, 768, 1536, 768);
    }
}

// Round 6
// 680.410 us; speedup vs baseline: 1.2534x; 1.0940x over previous
//
#include <hip/hip_runtime.h>
#include <hip/hip_bf16.h>
#include <math.h>

// Problem constants (fixed by reference)
#define D_MODEL   768
#define D_STATE   16
#define D_CONV    4
#define D_INNER   1536
#define DT_RANK   48
#define BATCH     4
#define SEQ_LEN   2048
#define BL        (BATCH * SEQ_LEN)        // 8192 rows
#define NCHUNK    32
#define CHUNK     (SEQ_LEN / NCHUNK)       // 64

typedef __bf16 bf16x8 __attribute__((ext_vector_type(8)));
typedef float  f32x4  __attribute__((ext_vector_type(4)));

__device__ __forceinline__ void async_copy16(const void* g, void* l) {
    __builtin_amdgcn_global_load_lds(
        (const __attribute__((address_space(1))) void*)g,
        (__attribute__((address_space(3))) void*)l,
        16, 0, 0);
}

// ---------------------------------------------------------------------------
// Split-bf16 MFMA GEMM (NT): C[m,n] = sum_k A[m,k]*B[n,k] in ~fp32 precision.
// A: M x 2K bf16 [A_hi | A_lo], B: N x 2K bf16 [B_hi | B_lo].
// C = Ah*Bh + Ah*Bl + Al*Bh (drops Al*Bl ~ 2^-18), computed as THREE
// CONTIGUOUS K sub-loops so inner-loop addresses are affine in kk (the R5
// per-iteration slice map defeated strength reduction -> VALUBusy 52%).
// 128x128 tile, BK=32, 4 waves of 64x64 (4x4 of 16x16x32 MFMA),
// global_load_lds width-16 staging, R5 global-side XOR swizzle retained.
// EPI 0: plain store.  EPI 1: softplus(v + bias[col]) (dt epilogue).
// M, N multiples of 128; K multiple of 32.
// ---------------------------------------------------------------------------
template <int EPI>
__global__ __launch_bounds__(256)
void gemm_split_nt(const __bf16* __restrict__ A, const __bf16* __restrict__ B,
                   float* __restrict__ C, const float* __restrict__ bias,
                   int M, int N, int K, int ldc)
{
    __shared__ __bf16 Asl[128 * 32];
    __shared__ __bf16 Bsl[128 * 32];

    const int tid  = threadIdx.x;
    const int lane = tid & 63;
    const int w    = tid >> 6;
    const int wm   = (w >> 1) * 64;
    const int wn   = (w & 1) * 64;

    const int bm = blockIdx.y * 128;
    const int bn = blockIdx.x * 128;

    const long lda = 2L * K;
    const long ldb = 2L * K;

    f32x4 acc[4][4];
    #pragma unroll
    for (int i = 0; i < 4; ++i)
        #pragma unroll
        for (int j = 0; j < 4; ++j)
            acc[i][j] = (f32x4){0.f, 0.f, 0.f, 0.f};

    // staging: wave w stages rows [w*32, w*32+32); lane l -> row w*32+(l>>2),
    // global k-chunk (l&3)^((l>>4)&3) (swizzle applied on the global side).
    const int srow = w * 32 + (lane >> 2);
    const int kc8  = (((lane & 3) ^ ((lane >> 4) & 3))) * 8;
    const __bf16* Abase = A + (long)(bm + srow) * lda + kc8;
    const __bf16* Bbase = B + (long)(bn + srow) * ldb + kc8;
    char* AslW = (char*)Asl + (w * 32) * 64;
    char* BslW = (char*)Bsl + (w * 32) * 64;

    const int rdK = (((lane >> 4) ^ ((lane >> 2) & 3))) * 8;
    const int fr  = lane & 15;
    const long lda16 = 16 * lda, ldb16 = 16 * ldb;

    // slice offsets: (A,B) in {(hi,hi),(hi,lo),(lo,hi)}
    const int aoff[3] = {0, 0, K};
    const int boff[3] = {0, K, 0};

    #pragma unroll
    for (int s = 0; s < 3; ++s) {
        const __bf16* Ab = Abase + aoff[s];
        const __bf16* Bb = Bbase + boff[s];
        for (int kk = 0; kk < K; kk += 32) {
            __syncthreads();
            async_copy16(Ab + kk,         AslW);
            async_copy16(Ab + lda16 + kk, AslW + 16 * 64);
            async_copy16(Bb + kk,         BslW);
            async_copy16(Bb + ldb16 + kk, BslW + 16 * 64);
            __syncthreads();

            bf16x8 af[4], bfr[4];
            #pragma unroll
            for (int t = 0; t < 4; ++t) {
                af[t]  = *(const bf16x8*)&Asl[(wm + t * 16 + fr) * 32 + rdK];
                bfr[t] = *(const bf16x8*)&Bsl[(wn + t * 16 + fr) * 32 + rdK];
            }
            #pragma unroll
            for (int i = 0; i < 4; ++i)
                #pragma unroll
                for (int j = 0; j < 4; ++j)
                    acc[i][j] = __builtin_amdgcn_mfma_f32_16x16x32_bf16(af[i], bfr[j], acc[i][j], 0, 0, 0);
        }
    }

    // C/D layout (m89-verified): col = lane&15, row = (lane>>4)*4 + reg
    const int cn  = lane & 15;
    const int cr4 = (lane >> 4) * 4;
    #pragma unroll
    for (int i = 0; i < 4; ++i)
        #pragma unroll
        for (int j = 0; j < 4; ++j)
            #pragma unroll
            for (int r = 0; r < 4; ++r) {
                const int row = bm + wm + i * 16 + cr4 + r;
                const int col = bn + wn + j * 16 + cn;
                float v = acc[i][j][r];
                if (EPI == 1) {
                    v += bias[col];
                    v = fmaxf(v, 0.f) + log1pf(__expf(-fabsf(v)));  // stable softplus
                }
                C[(long)row * ldc + col] = v;
            }
}

// ---------------------------------------------------------------------------
// x_dbl split-K MFMA GEMM: A = xcS (8192 x 3072 bf16 split), B = W_xS
// (128-row padded panel, 80 valid), K=1536, K'=4608 -> 144 k-tiles split 4.
// grid(4, 64); partials to Pout[s][8192][128].  3-slice segmented K walk
// (affine inner loop), same swizzle/staging as gemm_split_nt.
// ---------------------------------------------------------------------------
__global__ __launch_bounds__(256)
void gemm_xdbl(const __bf16* __restrict__ A, const __bf16* __restrict__ B,
               float* __restrict__ Pout)
{
    __shared__ __bf16 Asl[128 * 32];
    __shared__ __bf16 Bsl[128 * 32];

    const int tid  = threadIdx.x;
    const int lane = tid & 63;
    const int w    = tid >> 6;
    const int wm   = (w >> 1) * 64;
    const int wn   = (w & 1) * 64;

    const int s  = blockIdx.x;           // split-K index 0..3
    const int bm = blockIdx.y * 128;
    const long lda = 3072, ldb = 3072;
    const int K = 1536;

    f32x4 acc[4][4];
    #pragma unroll
    for (int i = 0; i < 4; ++i)
        #pragma unroll
        for (int j = 0; j < 4; ++j)
            acc[i][j] = (f32x4){0.f, 0.f, 0.f, 0.f};

    const int srow = w * 32 + (lane >> 2);
    const int kc8  = (((lane & 3) ^ ((lane >> 4) & 3))) * 8;
    const __bf16* Abase = A + (long)(bm + srow) * lda + kc8;
    const __bf16* Bbase = B + (long)srow * ldb + kc8;
    char* AslW = (char*)Asl + (w * 32) * 64;
    char* BslW = (char*)Bsl + (w * 32) * 64;

    const int rdK = (((lane >> 4) ^ ((lane >> 2) & 3))) * 8;
    const int fr  = lane & 15;
    const long lda16 = 16 * lda, ldb16 = 16 * ldb;

    const int aoff[3] = {0, 0, K};
    const int boff[3] = {0, K, 0};
    const int kt0 = s * 36, kt1 = kt0 + 36;   // of 144 total k-tiles (3*48)

    #pragma unroll
    for (int seg = 0; seg < 3; ++seg) {
        const int lo  = (kt0 > seg * 48)      ? kt0 : seg * 48;
        const int hiE = (kt1 < seg * 48 + 48) ? kt1 : seg * 48 + 48;
        const __bf16* Ab = Abase + aoff[seg];
        const __bf16* Bb = Bbase + boff[seg];
        for (int kt = lo; kt < hiE; ++kt) {
            const int kk = (kt - seg * 48) * 32;
            __syncthreads();
            async_copy16(Ab + kk,         AslW);
            async_copy16(Ab + lda16 + kk, AslW + 16 * 64);
            async_copy16(Bb + kk,         BslW);
            async_copy16(Bb + ldb16 + kk, BslW + 16 * 64);
            __syncthreads();

            bf16x8 af[4], bfr[4];
            #pragma unroll
            for (int t = 0; t < 4; ++t) {
                af[t]  = *(const bf16x8*)&Asl[(wm + t * 16 + fr) * 32 + rdK];
                bfr[t] = *(const bf16x8*)&Bsl[(wn + t * 16 + fr) * 32 + rdK];
            }
            #pragma unroll
            for (int i = 0; i < 4; ++i)
                #pragma unroll
                for (int j = 0; j < 4; ++j)
                    acc[i][j] = __builtin_amdgcn_mfma_f32_16x16x32_bf16(af[i], bfr[j], acc[i][j], 0, 0, 0);
        }
    }

    float* Cp = Pout + (long)s * (8192L * 128);
    const int cn  = lane & 15;
    const int cr4 = (lane >> 4) * 4;
    #pragma unroll
    for (int i = 0; i < 4; ++i)
        #pragma unroll
        for (int j = 0; j < 4; ++j)
            #pragma unroll
            for (int r = 0; r < 4; ++r) {
                const int row = bm + wm + i * 16 + cr4 + r;
                const int col = wn + j * 16 + cn;
                Cp[(long)row * 128 + col] = acc[i][j][r];
            }
}

// ---------------------------------------------------------------------------
// Reduce 4 split-K partials into xdbl (ld 80) AND emit split-bf16 A-operand
// xdtS (8192 x 128: hi of k 0..47 in cols 0..47, lo in 64..111, zeros pad)
// for the MFMA dt-GEMM.  One thread per (row, c in 0..127).
// ---------------------------------------------------------------------------
__global__ __launch_bounds__(256)
void xdbl_reduce2(const float* __restrict__ Pout, float* __restrict__ xdbl,
                  __bf16* __restrict__ xdtS)
{
    const long i = (long)blockIdx.x * 256 + threadIdx.x;   // over 8192*128
    if (i >= 8192L * 128) return;
    const long r  = i >> 7;
    const int  c  = (int)(i & 127);
    const long st = 8192L * 128;
    const long rb = r * 128;

    float v = 0.f;
    if (c < 80) {
        const long o = rb + c;
        v = (Pout[o] + Pout[o + st]) + (Pout[o + 2 * st] + Pout[o + 3 * st]);
        xdbl[r * 80 + c] = v;
    }
    const int k = c & 63;
    float u = 0.f;
    if (k < 48) {
        if (c < 48) {
            u = v;                     // same value this thread computed
        } else {
            const long o = rb + k;
            u = (Pout[o] + Pout[o + st]) + (Pout[o + 2 * st] + Pout[o + 3 * st]);
        }
    }
    const __bf16 hi = (__bf16)u;
    xdtS[rb + c] = (c < 64) ? hi : (__bf16)(u - (float)hi);
}

// ---------------------------------------------------------------------------
// fp32 -> split-bf16 [hi|lo] rows.  src: rows x K fp32, dst: rows x 2K bf16.
// ---------------------------------------------------------------------------
__global__ __launch_bounds__(256)
void split_bf16_kernel(const float* __restrict__ src, __bf16* __restrict__ dst,
                       int K, long n)
{
    const long i = (long)blockIdx.x * 256 + threadIdx.x;
    if (i >= n) return;
    const long row = i / K;
    const int  col = (int)(i - row * K);
    const float a = src[i];
    const __bf16 h = (__bf16)a;
    const __bf16 l = (__bf16)(a - (float)h);
    __bf16* d = dst + row * (2L * K) + col;
    d[0] = h;
    d[K] = l;
}

// ---------------------------------------------------------------------------
// Merged weight split: W_in (3072x768), W_out (768x1536), W_x (80x1536),
// W_dt (1536x48 -> padded 1536x128 split with zero k 48..63).
// ---------------------------------------------------------------------------
#define NW1 (3072L * 768)
#define NW2 (768L * 1536)
#define NW3 (80L * 1536)
#define NW4 (1536L * 128)
__global__ __launch_bounds__(256)
void split_weights(const float* __restrict__ W_in, const float* __restrict__ W_out,
                   const float* __restrict__ W_x, const float* __restrict__ W_dt,
                   __bf16* __restrict__ wInS, __bf16* __restrict__ wOutS,
                   __bf16* __restrict__ wXS, __bf16* __restrict__ wDtS)
{
    long i = (long)blockIdx.x * 256 + threadIdx.x;
    if (i < NW1) {
        const long row = i / 768; const int col = (int)(i - row * 768);
        const float a = W_in[i];
        const __bf16 h = (__bf16)a;
        __bf16* d = wInS + row * 1536 + col;
        d[0] = h; d[768] = (__bf16)(a - (float)h);
        return;
    }
    i -= NW1;
    if (i < NW2) {
        const long row = i / 1536; const int col = (int)(i - row * 1536);
        const float a = W_out[i];
        const __bf16 h = (__bf16)a;
        __bf16* d = wOutS + row * 3072 + col;
        d[0] = h; d[1536] = (__bf16)(a - (float)h);
        return;
    }
    i -= NW2;
    if (i < NW3) {
        const long row = i / 1536; const int col = (int)(i - row * 1536);
        const float a = W_x[i];
        const __bf16 h = (__bf16)a;
        __bf16* d = wXS + row * 3072 + col;
        d[0] = h; d[1536] = (__bf16)(a - (float)h);
        return;
    }
    i -= NW3;
    if (i < NW4) {
        const long row = i >> 7; const int c = (int)(i & 127);
        const int k = c & 63;
        const float a = (k < 48) ? W_dt[row * 48 + k] : 0.f;
        const __bf16 h = (__bf16)a;
        wDtS[row * 128 + c] = (c < 64) ? h : (__bf16)(a - (float)h);
    }
}

// ---------------------------------------------------------------------------
// Depthwise causal conv (width 4) + bias + SiLU -> xc fp32 AND xcS split-bf16.
// ---------------------------------------------------------------------------
__global__ __launch_bounds__(256)
void conv_silu_kernel(const float* __restrict__ xz,
                      const float* __restrict__ conv_w,
                      const float* __restrict__ conv_b,
                      float* __restrict__ xc,
                      __bf16* __restrict__ xcS)
{
    const long idx = (long)blockIdx.x * 256 + threadIdx.x;
    const int d  = (int)(idx % D_INNER);
    const long bl = idx / D_INNER;
    const int l  = (int)(bl % SEQ_LEN);

    const float w0 = conv_w[d * 4 + 0];
    const float w1 = conv_w[d * 4 + 1];
    const float w2 = conv_w[d * 4 + 2];
    const float w3 = conv_w[d * 4 + 3];

    const float* base = xz + bl * 3072 + d;
    float s = conv_b[d];
    if (l >= 3) s = fmaf(base[-3 * 3072], w0, s);
    if (l >= 2) s = fmaf(base[-2 * 3072], w1, s);
    if (l >= 1) s = fmaf(base[-1 * 3072], w2, s);
    s = fmaf(base[0], w3, s);
    const float sig = 1.f / (1.f + __expf(-s));
    const float v = s * sig;
    xc[bl * D_INNER + d] = v;
    const __bf16 hi = (__bf16)v;
    const __bf16 lo = (__bf16)(v - (float)hi);
    xcS[bl * 3072 + d]        = hi;
    xcS[bl * 3072 + 1536 + d] = lo;
}

// ---------------------------------------------------------------------------
// Scan phase A: per (b, d, chunk): P = prod(a_l), S = local scan (h0=0).
// ---------------------------------------------------------------------------
__global__ __launch_bounds__(256)
void scan_phaseA(const float* __restrict__ xc, const float* __restrict__ xz,
                 const float* __restrict__ xdbl, const float* __restrict__ A_log,
                 float* __restrict__ P, float* __restrict__ S)
{
    const int d = blockIdx.x * 256 + threadIdx.x;
    const int c = blockIdx.y;
    const int b = blockIdx.z;

    float An[16], Pr[16], Sr[16];
    #pragma unroll
    for (int n = 0; n < 16; ++n) {
        An[n] = -__expf(A_log[d * 16 + n]);
        Pr[n] = 1.f;
        Sr[n] = 0.f;
    }

    const long bl0 = (long)b * SEQ_LEN + (long)c * CHUNK;
    for (int l = 0; l < CHUNK; ++l) {
        const long bl = bl0 + l;
        const float dt  = xz[bl * 3072 + d];
        const float x   = xc[bl * D_INNER + d];
        const float dtx = dt * x;
        const float* bc = xdbl + bl * 80 + DT_RANK;
        #pragma unroll
        for (int n = 0; n < 16; ++n) {
            const float a = __expf(dt * An[n]);
            Pr[n] *= a;
            Sr[n] = fmaf(a, Sr[n], dtx * bc[n]);
        }
    }

    const long base = ((long)(b * NCHUNK + c) * 16) * D_INNER + d;
    #pragma unroll
    for (int n = 0; n < 16; ++n) {
        P[base + (long)n * D_INNER] = Pr[n];
        S[base + (long)n * D_INNER] = Sr[n];
    }
}

// ---------------------------------------------------------------------------
// Scan phase B: sequential chunk-combine per (b, d): H[c] = h_in for chunk c.
// ---------------------------------------------------------------------------
__global__ __launch_bounds__(256)
void scan_phaseB(const float* __restrict__ P, const float* __restrict__ S,
                 float* __restrict__ H)
{
    const int t = blockIdx.x * 256 + threadIdx.x;
    const int d = t % D_INNER;
    const int b = t / D_INNER;

    float h[16];
    #pragma unroll
    for (int n = 0; n < 16; ++n) h[n] = 0.f;

    for (int c = 0; c < NCHUNK; ++c) {
        const long base = ((long)(b * NCHUNK + c) * 16) * D_INNER + d;
        #pragma unroll
        for (int n = 0; n < 16; ++n) {
            const long i = base + (long)n * D_INNER;
            H[i] = h[n];
            h[n] = fmaf(P[i], h[n], S[i]);
        }
    }
}

// ---------------------------------------------------------------------------
// Scan phase C: re-run chunks from correct h_in, emit y, gate with silu(z),
// write y as split-bf16 [hi|lo] rows (row stride 3072) for the MFMA out-GEMM.
// ---------------------------------------------------------------------------
__global__ __launch_bounds__(256)
void scan_phaseC(const float* __restrict__ xc, const float* __restrict__ xz,
                 const float* __restrict__ xdbl, const float* __restrict__ A_log,
                 const float* __restrict__ Dp, const float* __restrict__ H,
                 __bf16* __restrict__ yS)
{
    const int d = blockIdx.x * 256 + threadIdx.x;
    const int c = blockIdx.y;
    const int b = blockIdx.z;

    float An[16], h[16];
    const long hbase = ((long)(b * NCHUNK + c) * 16) * D_INNER + d;
    #pragma unroll
    for (int n = 0; n < 16; ++n) {
        An[n] = -__expf(A_log[d * 16 + n]);
        h[n]  = H[hbase + (long)n * D_INNER];
    }
    const float Dd = Dp[d];

    const long bl0 = (long)b * SEQ_LEN + (long)c * CHUNK;
    for (int l = 0; l < CHUNK; ++l) {
        const long bl = bl0 + l;
        const float dt  = xz[bl * 3072 + d];
        const float x   = xc[bl * D_INNER + d];
        const float dtx = dt * x;
        const float* bc = xdbl + bl * 80 + DT_RANK;
        float y = Dd * x;
        #pragma unroll
        for (int n = 0; n < 16; ++n) {
            const float a = __expf(dt * An[n]);
            h[n] = fmaf(a, h[n], dtx * bc[n]);
            y = fmaf(h[n], bc[16 + n], y);
        }
        const float z  = xz[bl * 3072 + D_INNER + d];
        const float sz = z / (1.f + __expf(-z));
        const float v  = y * sz;
        const __bf16 hi = (__bf16)v;
        const __bf16 lo = (__bf16)(v - (float)hi);
        yS[bl * 3072 + d]        = hi;
        yS[bl * 3072 + 1536 + d] = lo;
    }
}

// ---------------------------------------------------------------------------
extern "C" void kernel_launch(void* const* d_in, const int* in_sizes, int n_in,
                              void* d_out, int out_size, void* d_ws, size_t ws_size,
                              hipStream_t stream)
{
    const float* x      = (const float*)d_in[0];   // (4,2048,768)
    const float* W_in   = (const float*)d_in[1];   // (3072,768)
    const float* conv_w = (const float*)d_in[2];   // (1536,1,4)
    const float* conv_b = (const float*)d_in[3];   // (1536,)
    const float* W_x    = (const float*)d_in[4];   // (80,1536)
    const float* W_dt   = (const float*)d_in[5];   // (1536,48)
    const float* b_dt   = (const float*)d_in[6];   // (1536,)
    const float* A_log  = (const float*)d_in[7];   // (1536,16)
    const float* D_p    = (const float*)d_in[8];   // (1536,)
    const float* W_out  = (const float*)d_in[9];   // (768,1536)
    float* out = (float*)d_out;                    // (4,2048,768)

    // ---- workspace carve (with region overlays), ~242 MB ----------------
    char* p = (char*)d_ws;
    auto take = [&](size_t bytes) { char* r = p; p += (bytes + 255) & ~(size_t)255; return r; };

    float*  xz    = (float*)take((size_t)BL * 3072 * 4);    // 100.7 MB (dt | z)
    float*  xc    = (float*)take((size_t)BL * 1536 * 4);    //  50.3 MB
    float*  xdbl  = (float*)take((size_t)BL * 80 * 4);      //   2.6 MB
    float*  H     = (float*)take((size_t)BATCH * NCHUNK * 16 * D_INNER * 4); // 12.6 MB
    __bf16* wOutS = (__bf16*)take(768L * 3072 * 2);         //   4.7 MB
    __bf16* wXS   = (__bf16*)take(128L * 3072 * 2);         //   0.8 MB (80 valid rows)
    __bf16* wDtS  = (__bf16*)take(1536L * 128 * 2);         //   0.4 MB
    __bf16* xdtS  = (__bf16*)take(8192L * 128 * 2);         //   2.1 MB
    float*  Pout  = (float*)take(4L * 8192 * 128 * 4);      //  16.8 MB split-K partials

    // REGION (50.4 MB), time-multiplexed:
    //   phase 1:   xS (25.2MB) + wInS (9.4MB)
    //   phase 2-3: xcS (8192x3072 bf16 = 50.3MB)
    //   phase 6-7: P (12.6MB) + S (12.6MB)
    //   phase 8-9: yS (50.3MB)
    char* region = take(50331648);
    __bf16* xS   = (__bf16*)region;
    __bf16* wInS = (__bf16*)(region + 25165824);
    __bf16* xcS  = (__bf16*)region;
    float*  P    = (float*)region;
    float*  S    = (float*)(region + 12582912);
    __bf16* yS   = (__bf16*)region;

    // 0) split conversions (x + all weights)
    {
        const long nx = (long)BL * 768;
        split_bf16_kernel<<<(int)((nx + 255) / 256), 256, 0, stream>>>(x, xS, 768, nx);
        const long nw = NW1 + NW2 + NW3 + NW4;
        split_weights<<<(int)((nw + 255) / 256), 256, 0, stream>>>(
            W_in, W_out, W_x, W_dt, wInS, wOutS, wXS, wDtS);
    }
    // 1) xz = x @ W_in^T via split-bf16 MFMA (M=8192, N=3072, K=768)
    {
        dim3 grid(3072 / 128, BL / 128);
        gemm_split_nt<0><<<grid, 256, 0, stream>>>(xS, wInS, xz, nullptr,
                                                   BL, 3072, 768, 3072);
    }
    // 2) depthwise conv + bias + SiLU -> xc (fp32) + xcS (split-bf16; overlays xS)
    {
        const long total = (long)BL * D_INNER;
        conv_silu_kernel<<<(int)(total / 256), 256, 0, stream>>>(xz, conv_w, conv_b, xc, xcS);
    }
    // 3) x_dbl split-K MFMA: Pout[s] = xcS @ wXS^T chunks  (grid 4x64)
    {
        dim3 grid(4, BL / 128);
        gemm_xdbl<<<grid, 256, 0, stream>>>(xcS, wXS, Pout);
    }
    // 4) reduce partials -> xdbl (ld 80) + xdtS (split-bf16 dt-GEMM operand)
    {
        const long n = 8192L * 128;
        xdbl_reduce2<<<(int)((n + 255) / 256), 256, 0, stream>>>(Pout, xdbl, xdtS);
    }
    // 5) dt = softplus(xdt @ W_dt^T + b_dt) via split-bf16 MFMA (K=64 padded)
    //    -> xz cols 0..1535
    {
        dim3 grid(1536 / 128, BL / 128);
        gemm_split_nt<1><<<grid, 256, 0, stream>>>(xdtS, wDtS, xz, b_dt,
                                                   BL, 1536, 64, 3072);
    }
    // 6) scan phase A  (P,S overlay region; xcS dead after phase 3)
    {
        dim3 grid(D_INNER / 256, NCHUNK, BATCH);
        scan_phaseA<<<grid, 256, 0, stream>>>(xc, xz, xdbl, A_log, P, S);
    }
    // 7) scan phase B
    scan_phaseB<<<(BATCH * D_INNER) / 256, 256, 0, stream>>>(P, S, H);
    // 8) scan phase C -> yS (split-bf16; P,S dead)
    {
        dim3 grid(D_INNER / 256, NCHUNK, BATCH);
        scan_phaseC<<<grid, 256, 0, stream>>>(xc, xz, xdbl, A_log, D_p, H, yS);
    }
    // 9) out = y @ W_out^T via split-bf16 MFMA (M=8192, N=768, K=1536)
    {
        dim3 grid(768 / 128, BL / 128);
        gemm_split_nt<0><<<grid, 256, 0, stream>>>(yS, wOutS, out, nullptr,
                                                   BL, 768, 1536, 768);
    }
}

// Round 7
// 671.689 us; speedup vs baseline: 1.2697x; 1.0130x over previous
//
#include <hip/hip_runtime.h>
#include <hip/hip_bf16.h>
#include <math.h>

// Problem constants (fixed by reference)
#define D_MODEL   768
#define D_STATE   16
#define D_CONV    4
#define D_INNER   1536
#define DT_RANK   48
#define BATCH     4
#define SEQ_LEN   2048
#define BL        (BATCH * SEQ_LEN)        // 8192 rows
#define NCHUNK    32
#define CHUNK     (SEQ_LEN / NCHUNK)       // 64

typedef __bf16 bf16x8 __attribute__((ext_vector_type(8)));
typedef float  f32x4  __attribute__((ext_vector_type(4)));

__device__ __forceinline__ void async_copy16(const void* g, void* l) {
    __builtin_amdgcn_global_load_lds(
        (const __attribute__((address_space(1))) void*)g,
        (__attribute__((address_space(3))) void*)l,
        16, 0, 0);
}

// ---------------------------------------------------------------------------
// Split-bf16 MFMA GEMM (NT): C[m,n] = sum_k A[m,k]*B[n,k] in ~fp32 precision.
// A: M x 2K bf16 [A_hi | A_lo], B: N x 2K bf16 [B_hi | B_lo].
// C = Ah*Bh + Ah*Bl + Al*Bh (drops Al*Bl ~ 2^-18), three contiguous K
// sub-loops (affine addresses). 128x128 tile, BK=32, 4 waves of 64x64.
//
// LDS swizzle (R7): slot s of row r holds global k-chunk s ^ (r&3).
//   staging: lane l -> row w*32+(l>>2), chunk (l&3)^((l>>2)&3)  [permutation
//            within one 64B row segment -> coalescing identical to R3]
//   read:    rdK = ((lane>>4) ^ (lane&3))*8  -> slot varies 0..3 within every
//            4-lane group (ds_read_b128 4-lane sub-phase model fitted to
//            R3/R5=1.416e7 vs R4=0 conflict counters; R5's (lane>>2)&3 term
//            was constant within 4-lane groups -> didn't move the counter).
// EPI 0: plain store.  EPI 1: softplus(v + bias[col]) (dt epilogue).
// ---------------------------------------------------------------------------
template <int EPI>
__global__ __launch_bounds__(256)
void gemm_split_nt(const __bf16* __restrict__ A, const __bf16* __restrict__ B,
                   float* __restrict__ C, const float* __restrict__ bias,
                   int M, int N, int K, int ldc)
{
    __shared__ __bf16 Asl[128 * 32];
    __shared__ __bf16 Bsl[128 * 32];

    const int tid  = threadIdx.x;
    const int lane = tid & 63;
    const int w    = tid >> 6;
    const int wm   = (w >> 1) * 64;
    const int wn   = (w & 1) * 64;

    const int bm = blockIdx.y * 128;
    const int bn = blockIdx.x * 128;

    const long lda = 2L * K;
    const long ldb = 2L * K;

    f32x4 acc[4][4];
    #pragma unroll
    for (int i = 0; i < 4; ++i)
        #pragma unroll
        for (int j = 0; j < 4; ++j)
            acc[i][j] = (f32x4){0.f, 0.f, 0.f, 0.f};

    const int srow = w * 32 + (lane >> 2);
    const int kc8  = (((lane & 3) ^ ((lane >> 2) & 3))) * 8;   // R7 swizzle
    const __bf16* Abase = A + (long)(bm + srow) * lda + kc8;
    const __bf16* Bbase = B + (long)(bn + srow) * ldb + kc8;
    char* AslW = (char*)Asl + (w * 32) * 64;
    char* BslW = (char*)Bsl + (w * 32) * 64;

    const int rdK = (((lane >> 4) ^ (lane & 3))) * 8;          // R7 read slot
    const int fr  = lane & 15;
    const long lda16 = 16 * lda, ldb16 = 16 * ldb;

    // slice offsets: (A,B) in {(hi,hi),(hi,lo),(lo,hi)}
    const int aoff[3] = {0, 0, K};
    const int boff[3] = {0, K, 0};

    #pragma unroll
    for (int s = 0; s < 3; ++s) {
        const __bf16* Ab = Abase + aoff[s];
        const __bf16* Bb = Bbase + boff[s];
        for (int kk = 0; kk < K; kk += 32) {
            __syncthreads();
            async_copy16(Ab + kk,         AslW);
            async_copy16(Ab + lda16 + kk, AslW + 16 * 64);
            async_copy16(Bb + kk,         BslW);
            async_copy16(Bb + ldb16 + kk, BslW + 16 * 64);
            __syncthreads();

            bf16x8 af[4], bfr[4];
            #pragma unroll
            for (int t = 0; t < 4; ++t) {
                af[t]  = *(const bf16x8*)&Asl[(wm + t * 16 + fr) * 32 + rdK];
                bfr[t] = *(const bf16x8*)&Bsl[(wn + t * 16 + fr) * 32 + rdK];
            }
            #pragma unroll
            for (int i = 0; i < 4; ++i)
                #pragma unroll
                for (int j = 0; j < 4; ++j)
                    acc[i][j] = __builtin_amdgcn_mfma_f32_16x16x32_bf16(af[i], bfr[j], acc[i][j], 0, 0, 0);
        }
    }

    // C/D layout (m89-verified): col = lane&15, row = (lane>>4)*4 + reg
    const int cn  = lane & 15;
    const int cr4 = (lane >> 4) * 4;
    #pragma unroll
    for (int i = 0; i < 4; ++i)
        #pragma unroll
        for (int j = 0; j < 4; ++j)
            #pragma unroll
            for (int r = 0; r < 4; ++r) {
                const int row = bm + wm + i * 16 + cr4 + r;
                const int col = bn + wn + j * 16 + cn;
                float v = acc[i][j][r];
                if (EPI == 1) {
                    v += bias[col];
                    v = fmaxf(v, 0.f) + log1pf(__expf(-fabsf(v)));  // stable softplus
                }
                C[(long)row * ldc + col] = v;
            }
}

// ---------------------------------------------------------------------------
// x_dbl split-K MFMA GEMM: A = xcS (8192 x 3072 bf16 split), B = W_xS
// (128-row padded panel, 80 valid), K=1536, K'=4608 -> 144 k-tiles split 4.
// grid(4, 64); partials to Pout[s][8192][128]. R7 swizzle.
// ---------------------------------------------------------------------------
__global__ __launch_bounds__(256)
void gemm_xdbl(const __bf16* __restrict__ A, const __bf16* __restrict__ B,
               float* __restrict__ Pout)
{
    __shared__ __bf16 Asl[128 * 32];
    __shared__ __bf16 Bsl[128 * 32];

    const int tid  = threadIdx.x;
    const int lane = tid & 63;
    const int w    = tid >> 6;
    const int wm   = (w >> 1) * 64;
    const int wn   = (w & 1) * 64;

    const int s  = blockIdx.x;           // split-K index 0..3
    const int bm = blockIdx.y * 128;
    const long lda = 3072, ldb = 3072;
    const int K = 1536;

    f32x4 acc[4][4];
    #pragma unroll
    for (int i = 0; i < 4; ++i)
        #pragma unroll
        for (int j = 0; j < 4; ++j)
            acc[i][j] = (f32x4){0.f, 0.f, 0.f, 0.f};

    const int srow = w * 32 + (lane >> 2);
    const int kc8  = (((lane & 3) ^ ((lane >> 2) & 3))) * 8;
    const __bf16* Abase = A + (long)(bm + srow) * lda + kc8;
    const __bf16* Bbase = B + (long)srow * ldb + kc8;
    char* AslW = (char*)Asl + (w * 32) * 64;
    char* BslW = (char*)Bsl + (w * 32) * 64;

    const int rdK = (((lane >> 4) ^ (lane & 3))) * 8;
    const int fr  = lane & 15;
    const long lda16 = 16 * lda, ldb16 = 16 * ldb;

    const int aoff[3] = {0, 0, K};
    const int boff[3] = {0, K, 0};
    const int kt0 = s * 36, kt1 = kt0 + 36;   // of 144 total k-tiles (3*48)

    #pragma unroll
    for (int seg = 0; seg < 3; ++seg) {
        const int lo  = (kt0 > seg * 48)      ? kt0 : seg * 48;
        const int hiE = (kt1 < seg * 48 + 48) ? kt1 : seg * 48 + 48;
        const __bf16* Ab = Abase + aoff[seg];
        const __bf16* Bb = Bbase + boff[seg];
        for (int kt = lo; kt < hiE; ++kt) {
            const int kk = (kt - seg * 48) * 32;
            __syncthreads();
            async_copy16(Ab + kk,         AslW);
            async_copy16(Ab + lda16 + kk, AslW + 16 * 64);
            async_copy16(Bb + kk,         BslW);
            async_copy16(Bb + ldb16 + kk, BslW + 16 * 64);
            __syncthreads();

            bf16x8 af[4], bfr[4];
            #pragma unroll
            for (int t = 0; t < 4; ++t) {
                af[t]  = *(const bf16x8*)&Asl[(wm + t * 16 + fr) * 32 + rdK];
                bfr[t] = *(const bf16x8*)&Bsl[(wn + t * 16 + fr) * 32 + rdK];
            }
            #pragma unroll
            for (int i = 0; i < 4; ++i)
                #pragma unroll
                for (int j = 0; j < 4; ++j)
                    acc[i][j] = __builtin_amdgcn_mfma_f32_16x16x32_bf16(af[i], bfr[j], acc[i][j], 0, 0, 0);
        }
    }

    float* Cp = Pout + (long)s * (8192L * 128);
    const int cn  = lane & 15;
    const int cr4 = (lane >> 4) * 4;
    #pragma unroll
    for (int i = 0; i < 4; ++i)
        #pragma unroll
        for (int j = 0; j < 4; ++j)
            #pragma unroll
            for (int r = 0; r < 4; ++r) {
                const int row = bm + wm + i * 16 + cr4 + r;
                const int col = wn + j * 16 + cn;
                Cp[(long)row * 128 + col] = acc[i][j][r];
            }
}

// ---------------------------------------------------------------------------
// Reduce 4 split-K partials into xdbl (ld 80) AND emit split-bf16 A-operand
// xdtS (8192 x 128: hi of k 0..47 in cols 0..47, lo in 64..111, zeros pad).
// ---------------------------------------------------------------------------
__global__ __launch_bounds__(256)
void xdbl_reduce2(const float* __restrict__ Pout, float* __restrict__ xdbl,
                  __bf16* __restrict__ xdtS)
{
    const long i = (long)blockIdx.x * 256 + threadIdx.x;   // over 8192*128
    if (i >= 8192L * 128) return;
    const long r  = i >> 7;
    const int  c  = (int)(i & 127);
    const long st = 8192L * 128;
    const long rb = r * 128;

    float v = 0.f;
    if (c < 80) {
        const long o = rb + c;
        v = (Pout[o] + Pout[o + st]) + (Pout[o + 2 * st] + Pout[o + 3 * st]);
        xdbl[r * 80 + c] = v;
    }
    const int k = c & 63;
    float u = 0.f;
    if (k < 48) {
        if (c < 48) {
            u = v;
        } else {
            const long o = rb + k;
            u = (Pout[o] + Pout[o + st]) + (Pout[o + 2 * st] + Pout[o + 3 * st]);
        }
    }
    const __bf16 hi = (__bf16)u;
    xdtS[rb + c] = (c < 64) ? hi : (__bf16)(u - (float)hi);
}

// ---------------------------------------------------------------------------
// Merged input/weight split: x (8192x768), W_in (3072x768), W_out (768x1536),
// W_x (80x1536), W_dt (1536x48 -> padded 1536x128 split, zero k 48..63).
// ---------------------------------------------------------------------------
#define NW0 ((long)BL * 768)
#define NW1 (3072L * 768)
#define NW2 (768L * 1536)
#define NW3 (80L * 1536)
#define NW4 (1536L * 128)
__global__ __launch_bounds__(256)
void split_all(const float* __restrict__ x,
               const float* __restrict__ W_in, const float* __restrict__ W_out,
               const float* __restrict__ W_x, const float* __restrict__ W_dt,
               __bf16* __restrict__ xS,
               __bf16* __restrict__ wInS, __bf16* __restrict__ wOutS,
               __bf16* __restrict__ wXS, __bf16* __restrict__ wDtS)
{
    long i = (long)blockIdx.x * 256 + threadIdx.x;
    if (i < NW0) {
        const long row = i / 768; const int col = (int)(i - row * 768);
        const float a = x[i];
        const __bf16 h = (__bf16)a;
        __bf16* d = xS + row * 1536 + col;
        d[0] = h; d[768] = (__bf16)(a - (float)h);
        return;
    }
    i -= NW0;
    if (i < NW1) {
        const long row = i / 768; const int col = (int)(i - row * 768);
        const float a = W_in[i];
        const __bf16 h = (__bf16)a;
        __bf16* d = wInS + row * 1536 + col;
        d[0] = h; d[768] = (__bf16)(a - (float)h);
        return;
    }
    i -= NW1;
    if (i < NW2) {
        const long row = i / 1536; const int col = (int)(i - row * 1536);
        const float a = W_out[i];
        const __bf16 h = (__bf16)a;
        __bf16* d = wOutS + row * 3072 + col;
        d[0] = h; d[1536] = (__bf16)(a - (float)h);
        return;
    }
    i -= NW2;
    if (i < NW3) {
        const long row = i / 1536; const int col = (int)(i - row * 1536);
        const float a = W_x[i];
        const __bf16 h = (__bf16)a;
        __bf16* d = wXS + row * 3072 + col;
        d[0] = h; d[1536] = (__bf16)(a - (float)h);
        return;
    }
    i -= NW3;
    if (i < NW4) {
        const long row = i >> 7; const int c = (int)(i & 127);
        const int k = c & 63;
        const float a = (k < 48) ? W_dt[row * 48 + k] : 0.f;
        const __bf16 h = (__bf16)a;
        wDtS[row * 128 + c] = (c < 64) ? h : (__bf16)(a - (float)h);
    }
}

// ---------------------------------------------------------------------------
// Depthwise causal conv (width 4) + bias + SiLU -> xcS split-bf16 only
// (fp32 xc eliminated; scans reconstruct x = hi+lo, error ~2^-17).
// ---------------------------------------------------------------------------
__global__ __launch_bounds__(256)
void conv_silu_kernel(const float* __restrict__ xz,
                      const float* __restrict__ conv_w,
                      const float* __restrict__ conv_b,
                      __bf16* __restrict__ xcS)
{
    const long idx = (long)blockIdx.x * 256 + threadIdx.x;
    const int d  = (int)(idx % D_INNER);
    const long bl = idx / D_INNER;
    const int l  = (int)(bl % SEQ_LEN);

    const float w0 = conv_w[d * 4 + 0];
    const float w1 = conv_w[d * 4 + 1];
    const float w2 = conv_w[d * 4 + 2];
    const float w3 = conv_w[d * 4 + 3];

    const float* base = xz + bl * 3072 + d;
    float s = conv_b[d];
    if (l >= 3) s = fmaf(base[-3 * 3072], w0, s);
    if (l >= 2) s = fmaf(base[-2 * 3072], w1, s);
    if (l >= 1) s = fmaf(base[-1 * 3072], w2, s);
    s = fmaf(base[0], w3, s);
    const float sig = 1.f / (1.f + __expf(-s));
    const float v = s * sig;
    const __bf16 hi = (__bf16)v;
    const __bf16 lo = (__bf16)(v - (float)hi);
    xcS[bl * 3072 + d]        = hi;
    xcS[bl * 3072 + 1536 + d] = lo;
}

// ---------------------------------------------------------------------------
// Scan phase A: per (b, d, chunk): P = prod(a_l), S = local scan (h0=0).
// ---------------------------------------------------------------------------
__global__ __launch_bounds__(256)
void scan_phaseA(const __bf16* __restrict__ xcS, const float* __restrict__ xz,
                 const float* __restrict__ xdbl, const float* __restrict__ A_log,
                 float* __restrict__ P, float* __restrict__ S)
{
    const int d = blockIdx.x * 256 + threadIdx.x;
    const int c = blockIdx.y;
    const int b = blockIdx.z;

    float An[16], Pr[16], Sr[16];
    #pragma unroll
    for (int n = 0; n < 16; ++n) {
        An[n] = -__expf(A_log[d * 16 + n]);
        Pr[n] = 1.f;
        Sr[n] = 0.f;
    }

    const long bl0 = (long)b * SEQ_LEN + (long)c * CHUNK;
    for (int l = 0; l < CHUNK; ++l) {
        const long bl = bl0 + l;
        const float dt  = xz[bl * 3072 + d];
        const float x   = (float)xcS[bl * 3072 + d] + (float)xcS[bl * 3072 + 1536 + d];
        const float dtx = dt * x;
        const float* bc = xdbl + bl * 80 + DT_RANK;
        #pragma unroll
        for (int n = 0; n < 16; ++n) {
            const float a = __expf(dt * An[n]);
            Pr[n] *= a;
            Sr[n] = fmaf(a, Sr[n], dtx * bc[n]);
        }
    }

    const long base = ((long)(b * NCHUNK + c) * 16) * D_INNER + d;
    #pragma unroll
    for (int n = 0; n < 16; ++n) {
        P[base + (long)n * D_INNER] = Pr[n];
        S[base + (long)n * D_INNER] = Sr[n];
    }
}

// ---------------------------------------------------------------------------
// Scan phase B: sequential chunk-combine per (b, d): H[c] = h_in for chunk c.
// ---------------------------------------------------------------------------
__global__ __launch_bounds__(256)
void scan_phaseB(const float* __restrict__ P, const float* __restrict__ S,
                 float* __restrict__ H)
{
    const int t = blockIdx.x * 256 + threadIdx.x;
    const int d = t % D_INNER;
    const int b = t / D_INNER;

    float h[16];
    #pragma unroll
    for (int n = 0; n < 16; ++n) h[n] = 0.f;

    for (int c = 0; c < NCHUNK; ++c) {
        const long base = ((long)(b * NCHUNK + c) * 16) * D_INNER + d;
        #pragma unroll
        for (int n = 0; n < 16; ++n) {
            const long i = base + (long)n * D_INNER;
            H[i] = h[n];
            h[n] = fmaf(P[i], h[n], S[i]);
        }
    }
}

// ---------------------------------------------------------------------------
// Scan phase C: re-run chunks from correct h_in, emit y, gate with silu(z),
// write y as split-bf16 IN-PLACE over xcS (same (bl,d) element, read-before-
// write within the owning thread) -> yS for the MFMA out-GEMM.
// ---------------------------------------------------------------------------
__global__ __launch_bounds__(256)
void scan_phaseC(__bf16* xcS_yS, const float* __restrict__ xz,
                 const float* __restrict__ xdbl, const float* __restrict__ A_log,
                 const float* __restrict__ Dp, const float* __restrict__ H)
{
    const int d = blockIdx.x * 256 + threadIdx.x;
    const int c = blockIdx.y;
    const int b = blockIdx.z;

    float An[16], h[16];
    const long hbase = ((long)(b * NCHUNK + c) * 16) * D_INNER + d;
    #pragma unroll
    for (int n = 0; n < 16; ++n) {
        An[n] = -__expf(A_log[d * 16 + n]);
        h[n]  = H[hbase + (long)n * D_INNER];
    }
    const float Dd = Dp[d];

    const long bl0 = (long)b * SEQ_LEN + (long)c * CHUNK;
    for (int l = 0; l < CHUNK; ++l) {
        const long bl = bl0 + l;
        const float dt  = xz[bl * 3072 + d];
        const float x   = (float)xcS_yS[bl * 3072 + d] + (float)xcS_yS[bl * 3072 + 1536 + d];
        const float dtx = dt * x;
        const float* bc = xdbl + bl * 80 + DT_RANK;
        float y = Dd * x;
        #pragma unroll
        for (int n = 0; n < 16; ++n) {
            const float a = __expf(dt * An[n]);
            h[n] = fmaf(a, h[n], dtx * bc[n]);
            y = fmaf(h[n], bc[16 + n], y);
        }
        const float z  = xz[bl * 3072 + D_INNER + d];
        const float sz = z / (1.f + __expf(-z));
        const float v  = y * sz;
        const __bf16 hi = (__bf16)v;
        const __bf16 lo = (__bf16)(v - (float)hi);
        xcS_yS[bl * 3072 + d]        = hi;
        xcS_yS[bl * 3072 + 1536 + d] = lo;
    }
}

// ---------------------------------------------------------------------------
extern "C" void kernel_launch(void* const* d_in, const int* in_sizes, int n_in,
                              void* d_out, int out_size, void* d_ws, size_t ws_size,
                              hipStream_t stream)
{
    const float* x      = (const float*)d_in[0];   // (4,2048,768)
    const float* W_in   = (const float*)d_in[1];   // (3072,768)
    const float* conv_w = (const float*)d_in[2];   // (1536,1,4)
    const float* conv_b = (const float*)d_in[3];   // (1536,)
    const float* W_x    = (const float*)d_in[4];   // (80,1536)
    const float* W_dt   = (const float*)d_in[5];   // (1536,48)
    const float* b_dt   = (const float*)d_in[6];   // (1536,)
    const float* A_log  = (const float*)d_in[7];   // (1536,16)
    const float* D_p    = (const float*)d_in[8];   // (1536,)
    const float* W_out  = (const float*)d_in[9];   // (768,1536)
    float* out = (float*)d_out;                    // (4,2048,768)

    // ---- workspace carve, ~204 MB ---------------------------------------
    char* p = (char*)d_ws;
    auto take = [&](size_t bytes) { char* r = p; p += (bytes + 255) & ~(size_t)255; return r; };

    float*  xz    = (float*)take((size_t)BL * 3072 * 4);    // 100.7 MB (dt | z)
    float*  xdbl  = (float*)take((size_t)BL * 80 * 4);      //   2.6 MB
    float*  H     = (float*)take((size_t)BATCH * NCHUNK * 16 * D_INNER * 4); // 12.6 MB
    __bf16* wOutS = (__bf16*)take(768L * 3072 * 2);         //   4.7 MB
    __bf16* wXS   = (__bf16*)take(128L * 3072 * 2);         //   0.8 MB (80 valid)
    __bf16* wDtS  = (__bf16*)take(1536L * 128 * 2);         //   0.4 MB
    __bf16* xdtS  = (__bf16*)take(8192L * 128 * 2);         //   2.1 MB
    float*  Pout  = (float*)take(4L * 8192 * 128 * 4);      //  16.8 MB (-> P overlay)
    float*  S     = (float*)take((size_t)BATCH * NCHUNK * 16 * D_INNER * 4); // 12.6 MB
    float*  P     = Pout;   // Pout dead after xdbl_reduce2; P needs 12.6 MB

    // REGION (50.4 MB), time-multiplexed:
    //   phase 1:   xS (25.2MB) + wInS (9.4MB)
    //   phase 2-8: xcS (8192x3072 bf16 = 50.3MB), phaseC overwrites in-place -> yS
    char* region = take(50331648);
    __bf16* xS   = (__bf16*)region;
    __bf16* wInS = (__bf16*)(region + 25165824);
    __bf16* xcS  = (__bf16*)region;
    __bf16* yS   = (__bf16*)region;

    // 0) split conversions (x + all weights, one launch)
    {
        const long n = NW0 + NW1 + NW2 + NW3 + NW4;
        split_all<<<(int)((n + 255) / 256), 256, 0, stream>>>(
            x, W_in, W_out, W_x, W_dt, xS, wInS, wOutS, wXS, wDtS);
    }
    // 1) xz = x @ W_in^T via split-bf16 MFMA (M=8192, N=3072, K=768)
    {
        dim3 grid(3072 / 128, BL / 128);
        gemm_split_nt<0><<<grid, 256, 0, stream>>>(xS, wInS, xz, nullptr,
                                                   BL, 3072, 768, 3072);
    }
    // 2) depthwise conv + bias + SiLU -> xcS (split-bf16; overlays xS)
    {
        const long total = (long)BL * D_INNER;
        conv_silu_kernel<<<(int)(total / 256), 256, 0, stream>>>(xz, conv_w, conv_b, xcS);
    }
    // 3) x_dbl split-K MFMA: Pout[s] = xcS @ wXS^T chunks  (grid 4x64)
    {
        dim3 grid(4, BL / 128);
        gemm_xdbl<<<grid, 256, 0, stream>>>(xcS, wXS, Pout);
    }
    // 4) reduce partials -> xdbl (ld 80) + xdtS (split-bf16 dt-GEMM operand)
    {
        const long n = 8192L * 128;
        xdbl_reduce2<<<(int)((n + 255) / 256), 256, 0, stream>>>(Pout, xdbl, xdtS);
    }
    // 5) dt = softplus(xdt @ W_dt^T + b_dt) via split-bf16 MFMA (K=64 padded)
    {
        dim3 grid(1536 / 128, BL / 128);
        gemm_split_nt<1><<<grid, 256, 0, stream>>>(xdtS, wDtS, xz, b_dt,
                                                   BL, 1536, 64, 3072);
    }
    // 6) scan phase A  (P overlays dead Pout)
    {
        dim3 grid(D_INNER / 256, NCHUNK, BATCH);
        scan_phaseA<<<grid, 256, 0, stream>>>(xcS, xz, xdbl, A_log, P, S);
    }
    // 7) scan phase B
    scan_phaseB<<<(BATCH * D_INNER) / 256, 256, 0, stream>>>(P, S, H);
    // 8) scan phase C: xcS -> yS in-place
    {
        dim3 grid(D_INNER / 256, NCHUNK, BATCH);
        scan_phaseC<<<grid, 256, 0, stream>>>(xcS, xz, xdbl, A_log, D_p, H);
    }
    // 9) out = y @ W_out^T via split-bf16 MFMA (M=8192, N=768, K=1536)
    {
        dim3 grid(768 / 128, BL / 128);
        gemm_split_nt<0><<<grid, 256, 0, stream>>>(yS, wOutS, out, nullptr,
                                                   BL, 768, 1536, 768);
    }
}